// Round 7
// baseline (374.701 us; speedup 1.0000x reference)
//
#include <hip/hip_runtime.h>
#include <hip/hip_bf16.h>
#include <stdint.h>

typedef __attribute__((ext_vector_type(8))) __bf16 bf16x8;
typedef __attribute__((ext_vector_type(4))) float f32x4;
typedef __attribute__((ext_vector_type(16))) float f32x16;
typedef __attribute__((ext_vector_type(4))) unsigned int u32x4;

#define HIDDEN 1024
#define HEADS 16
#define HD 64
#define NB 4
#define T_ 2048
#define M_ROWS (NB * T_)  // 8192
#define SCL2 0.18033688f  // log2(e)/sqrt(64), applied in-kernel (round-1 proven)

__device__ __forceinline__ unsigned short f2bf(float x) {
  unsigned u = __builtin_bit_cast(unsigned, x);
  u += 0x7fff + ((u >> 16) & 1);
  return (unsigned short)(u >> 16);
}

// pack two f32 -> two bf16 (round-half-up) in one u32 via v_perm
__device__ __forceinline__ unsigned pk2(float a, float b) {
  unsigned ua = __builtin_bit_cast(unsigned, a) + 0x8000u;
  unsigned ub = __builtin_bit_cast(unsigned, b) + 0x8000u;
  return __builtin_amdgcn_perm(ub, ua, 0x07060302);
}

__device__ __forceinline__ f32x4 mfma16(bf16x8 a, bf16x8 b, f32x4 c) {
  return __builtin_amdgcn_mfma_f32_16x16x32_bf16(a, b, c, 0, 0, 0);
}
__device__ __forceinline__ f32x16 mfma32(bf16x8 a, bf16x8 b, f32x16 c) {
  return __builtin_amdgcn_mfma_f32_32x32x16_bf16(a, b, c, 0, 0, 0);
}

__device__ __forceinline__ void lds16(const void* g, void* l) {
  __builtin_amdgcn_global_load_lds(
      (const __attribute__((address_space(1))) unsigned int*)g,
      (__attribute__((address_space(3))) unsigned int*)l, 16, 0, 0);
}

__device__ __forceinline__ bf16x8 ldg8(const unsigned short* p) {
  return __builtin_bit_cast(bf16x8, *(const u32x4*)p);
}

// ---------------- f32 -> bf16 convert ----------------
__global__ void cvt_bf16(const float* __restrict__ in,
                         unsigned short* __restrict__ out, int n4) {
  int i = blockIdx.x * blockDim.x + threadIdx.x;
  int stride = gridDim.x * blockDim.x;
  for (; i < n4; i += stride) {
    float4 v = ((const float4*)in)[i];
    ushort4 o;
    o.x = f2bf(v.x); o.y = f2bf(v.y); o.z = f2bf(v.z); o.w = f2bf(v.w);
    ((ushort4*)out)[i] = o;
  }
}

// ---------------- 128x128 MFMA GEMM, C = A * B^T (+bias), m97 structure ----
template <int EPI>
__global__ __launch_bounds__(256) void gemm_bt(
    const unsigned short* __restrict__ A, const unsigned short* __restrict__ Bm,
    const float* __restrict__ bias, unsigned short* __restrict__ Qb,
    unsigned short* __restrict__ Kb, unsigned short* __restrict__ Vtb,
    float* __restrict__ Cf, int M, int N, int K) {
  __shared__ __align__(16) unsigned short Al[128 * 32];
  __shared__ __align__(16) unsigned short Bl[128 * 32];
  const int tid = threadIdx.x;
  const int w = tid >> 6, lane = tid & 63;
  const int l16 = lane & 15, grp = lane >> 4;
  const int brow0 = blockIdx.y * 128;
  const int bcol0 = blockIdx.x * 128;
  const int wrow = (w >> 1) * 64, wcol = (w & 1) * 64;

  f32x4 acc[4][4];
#pragma unroll
  for (int i = 0; i < 4; i++)
#pragma unroll
    for (int j = 0; j < 4; j++) acc[i][j] = (f32x4){0.f, 0.f, 0.f, 0.f};

  for (int k0 = 0; k0 < K; k0 += 32) {
    __syncthreads();
#pragma unroll
    for (int i = 0; i < 2; i++) {
      int off = (w * 2 + i) * 1024 + lane * 16;  // byte offset in 8KB tile
      int row = off >> 6;
      int cole = (off & 63) >> 1;
      lds16(A + (size_t)(brow0 + row) * K + k0 + cole,
            (char*)Al + (w * 2 + i) * 1024);
      lds16(Bm + (size_t)(bcol0 + row) * K + k0 + cole,
            (char*)Bl + (w * 2 + i) * 1024);
    }
    __syncthreads();
    bf16x8 av[4], bv[4];
#pragma unroll
    for (int m = 0; m < 4; m++)
      av[m] = __builtin_bit_cast(
          bf16x8, *(const u32x4*)&Al[(wrow + m * 16 + l16) * 32 + grp * 8]);
#pragma unroll
    for (int n = 0; n < 4; n++)
      bv[n] = __builtin_bit_cast(
          bf16x8, *(const u32x4*)&Bl[(wcol + n * 16 + l16) * 32 + grp * 8]);
#pragma unroll
    for (int m = 0; m < 4; m++)
#pragma unroll
      for (int n = 0; n < 4; n++) acc[m][n] = mfma16(av[m], bv[n], acc[m][n]);
  }

#pragma unroll
  for (int m = 0; m < 4; m++) {
#pragma unroll
    for (int n = 0; n < 4; n++) {
      int col = bcol0 + wcol + n * 16 + l16;
      int row0 = brow0 + wrow + m * 16 + grp * 4;
      float bs = bias[col];
      if (EPI == 0) {
        int part = col >> 10, rem = col & 1023;
        int h = rem >> 6, d = rem & 63;
#pragma unroll
        for (int r = 0; r < 4; r++) {
          int rw = row0 + r;
          int b = rw >> 11, t = rw & 2047;
          unsigned short val = f2bf(acc[m][n][r] + bs);
          size_t bh = (size_t)(b * 16 + h);
          if (part == 0)
            Qb[(bh * T_ + t) * HD + d] = val;
          else if (part == 1)
            Kb[(bh * T_ + t) * HD + d] = val;
          else
            Vtb[(bh * HD + d) * T_ + t] = val;
        }
      } else {
#pragma unroll
        for (int r = 0; r < 4; r++)
          Cf[(size_t)(row0 + r) * N + col] = acc[m][n][r] + bs;
      }
    }
  }
}

// ---------------- causal flash attention, swapped 32x32x16 ----------------
// 4096 one-wave blocks (64 thr). Wave = one 32-row query tile. Mapping:
// xcd=i&7, bh=xcd+8*(j&7), qt=63-(j>>3): heavy-first per XCD, 8 heads/XCD
// (4MB K/V L2-fit). K/V reg-double-buffered prefetch. All cross-lane ops
// are the proven __shfl_xor(.,32) forms; NO permlane self-swap (r2-r5:
// miscompiles when both operands alias one register).

#define PF(KF, VF, KC)                                          \
  do {                                                          \
    int kt_ = (KC) * 32;                                        \
    KF[0] = ldg8(&Kh[(size_t)(kt_ + l31) * HD + hi * 8]);       \
    KF[1] = ldg8(&Kh[(size_t)(kt_ + l31) * HD + 16 + hi * 8]);  \
    KF[2] = ldg8(&Kh[(size_t)(kt_ + l31) * HD + 32 + hi * 8]);  \
    KF[3] = ldg8(&Kh[(size_t)(kt_ + l31) * HD + 48 + hi * 8]);  \
    VF[0] = ldg8(&Vh[(size_t)l31 * T_ + kt_ + hi * 8]);         \
    VF[1] = ldg8(&Vh[(size_t)l31 * T_ + kt_ + 16 + hi * 8]);    \
    VF[2] = ldg8(&Vh[(size_t)(32 + l31) * T_ + kt_ + hi * 8]);  \
    VF[3] = ldg8(&Vh[(size_t)(32 + l31) * T_ + kt_ + 16 + hi * 8]); \
  } while (0)

#define CHUNK(KF, VF, MASKED)                                                \
  do {                                                                       \
    f32x16 sa;                                                               \
    _Pragma("unroll") for (int r = 0; r < 16; r++) sa[r] = 0.f;              \
    sa = mfma32(KF[0], qf[0], sa);                                           \
    sa = mfma32(KF[1], qf[1], sa);                                           \
    sa = mfma32(KF[2], qf[2], sa);                                           \
    sa = mfma32(KF[3], qf[3], sa);                                           \
    float sv[16];                                                            \
    _Pragma("unroll") for (int r = 0; r < 16; r++) {                         \
      sv[r] = sa[r] * SCL2;                                                  \
      if (MASKED) {                                                          \
        int key = (r & 3) + 8 * (r >> 2) + 4 * hi;                           \
        if (key > l31) sv[r] = -1e30f;                                       \
      }                                                                      \
    }                                                                        \
    float mx = sv[0];                                                        \
    _Pragma("unroll") for (int r = 1; r < 16; r++) mx = fmaxf(mx, sv[r]);    \
    mx = fmaxf(mx, __shfl_xor(mx, 32));                                      \
    if (mx > rm + 10.f) { /* defer-max */                                    \
      float c = exp2f(rm - mx);                                              \
      rl *= c;                                                               \
      _Pragma("unroll") for (int r = 0; r < 16; r++) {                       \
        o0[r] *= c;                                                          \
        o1[r] *= c;                                                          \
      }                                                                      \
      rm = mx;                                                               \
    }                                                                        \
    float rs = 0.f, pv[16];                                                  \
    _Pragma("unroll") for (int r = 0; r < 16; r++) {                         \
      pv[r] = exp2f(sv[r] - rm);                                             \
      rs += pv[r];                                                           \
    }                                                                        \
    rs += __shfl_xor(rs, 32);                                                \
    rl += rs;                                                                \
    unsigned wd[8], xd[8];                                                   \
    _Pragma("unroll") for (int j = 0; j < 8; j++)                            \
        wd[j] = pk2(pv[2 * j], pv[2 * j + 1]);                               \
    _Pragma("unroll") for (int j = 0; j < 8; j++)                            \
        xd[j] = (unsigned)__shfl_xor((int)wd[j], 32);                        \
    u32x4 pa0u, pa1u;                                                        \
    pa0u.x = hi ? xd[2] : wd[0];                                             \
    pa0u.y = hi ? xd[3] : wd[1];                                             \
    pa0u.z = hi ? wd[2] : xd[0];                                             \
    pa0u.w = hi ? wd[3] : xd[1];                                             \
    pa1u.x = hi ? xd[6] : wd[4];                                             \
    pa1u.y = hi ? xd[7] : wd[5];                                             \
    pa1u.z = hi ? wd[6] : xd[4];                                             \
    pa1u.w = hi ? wd[7] : xd[5];                                             \
    bf16x8 pa0 = __builtin_bit_cast(bf16x8, pa0u);                           \
    bf16x8 pa1 = __builtin_bit_cast(bf16x8, pa1u);                           \
    o0 = mfma32(VF[0], pa0, o0);                                             \
    o0 = mfma32(VF[1], pa1, o0);                                             \
    o1 = mfma32(VF[2], pa0, o1);                                             \
    o1 = mfma32(VF[3], pa1, o1);                                             \
  } while (0)

__global__ __launch_bounds__(64, 4) void attn32(
    const unsigned short* __restrict__ Q, const unsigned short* __restrict__ K,
    const unsigned short* __restrict__ Vt, unsigned short* __restrict__ Ao) {
  const int i = blockIdx.x;
  const int xcd = i & 7, j = i >> 3;           // j 0..511
  const int bh = xcd + 8 * (j & 7);            // 8 heads per XCD: K/V L2-fit
  const int qt = 63 - (j >> 3);                // heavy query tiles first
  const int lane = threadIdx.x & 63;
  const int l31 = lane & 31, hi = lane >> 5;
  const unsigned short* Qh = Q + (size_t)bh * T_ * HD;
  const unsigned short* Kh = K + (size_t)bh * T_ * HD;
  const unsigned short* Vh = Vt + (size_t)bh * HD * T_;
  const int b_ = bh >> 4, h_ = bh & 15;

  bf16x8 qf[4], kA[4], vA[4], kB[4], vB[4];
  f32x16 o0, o1;
  float rm, rl;

  const int qbase = qt * 32;
#pragma unroll
  for (int st = 0; st < 4; st++)
    qf[st] = ldg8(&Qh[(size_t)(qbase + l31) * HD + st * 16 + hi * 8]);
#pragma unroll
  for (int r = 0; r < 16; r++) { o0[r] = 0.f; o1[r] = 0.f; }
  rm = -1e30f;
  rl = 0.f;

  PF(kA, vA, 0);
  int kc = 0;
  while (kc + 2 <= qt) {
    PF(kB, vB, kc + 1);
    CHUNK(kA, vA, 0);
    PF(kA, vA, kc + 2);
    CHUNK(kB, vB, 0);
    kc += 2;
  }
  if (kc < qt) {
    PF(kB, vB, kc + 1);
    CHUNK(kA, vA, 0);
    CHUNK(kB, vB, 1);
  } else {
    CHUNK(kA, vA, 1);
  }

  float inv = 1.f / rl;
  const size_t base = ((size_t)b_ * T_ + qbase + l31) * HIDDEN + h_ * HD + hi * 4;
#pragma unroll
  for (int g = 0; g < 4; g++) {
    uint2 u;
    u.x = pk2(o0[4 * g] * inv, o0[4 * g + 1] * inv);
    u.y = pk2(o0[4 * g + 2] * inv, o0[4 * g + 3] * inv);
    *(uint2*)&Ao[base + g * 8] = u;
  }
#pragma unroll
  for (int g = 0; g < 4; g++) {
    uint2 u;
    u.x = pk2(o1[4 * g] * inv, o1[4 * g + 1] * inv);
    u.y = pk2(o1[4 * g + 2] * inv, o1[4 * g + 3] * inv);
    *(uint2*)&Ao[base + 32 + g * 8] = u;
  }
}

extern "C" void kernel_launch(void* const* d_in, const int* in_sizes, int n_in,
                              void* d_out, int out_size, void* d_ws,
                              size_t ws_size, hipStream_t stream) {
  const float* data = (const float*)d_in[0];
  const float* qkvw = (const float*)d_in[1];
  const float* qkvb = (const float*)d_in[2];
  const float* outw = (const float*)d_in[3];
  const float* outb = (const float*)d_in[4];
  float* out = (float*)d_out;
  char* ws = (char*)d_ws;

  unsigned short* dataBf = (unsigned short*)(ws);             // 16 MiB, reused as attnO
  unsigned short* qkvwBf = (unsigned short*)(ws + 16777216);  // 6 MiB
  unsigned short* outwBf = (unsigned short*)(ws + 23068672);  // 2 MiB
  unsigned short* Qb = (unsigned short*)(ws + 25165824);      // 16 MiB
  unsigned short* Kb = (unsigned short*)(ws + 41943040);      // 16 MiB
  unsigned short* Vtb = (unsigned short*)(ws + 58720256);     // 16 MiB
  unsigned short* attnO = dataBf;  // safe: dataBf dead after QKV GEMM

  cvt_bf16<<<2048, 256, 0, stream>>>(data, dataBf, (M_ROWS * HIDDEN) / 4);
  cvt_bf16<<<1024, 256, 0, stream>>>(qkvw, qkvwBf, (3 * HIDDEN * HIDDEN) / 4);
  cvt_bf16<<<512, 256, 0, stream>>>(outw, outwBf, (HIDDEN * HIDDEN) / 4);

  gemm_bt<0><<<dim3(24, 64), 256, 0, stream>>>(dataBf, qkvwBf, qkvb, Qb, Kb,
                                               Vtb, nullptr, M_ROWS, 3 * HIDDEN,
                                               HIDDEN);
  attn32<<<4096, 64, 0, stream>>>(Qb, Kb, Vtb, attnO);
  gemm_bt<1><<<dim3(8, 64), 256, 0, stream>>>(attnO, outwBf, outb, nullptr,
                                              nullptr, nullptr, out, M_ROWS,
                                              HIDDEN, HIDDEN);
}

// Round 8
// 294.787 us; speedup vs baseline: 1.2711x; 1.2711x over previous
//
#include <hip/hip_runtime.h>
#include <hip/hip_bf16.h>
#include <stdint.h>

typedef __attribute__((ext_vector_type(8))) __bf16 bf16x8;
typedef __attribute__((ext_vector_type(4))) float f32x4;
typedef __attribute__((ext_vector_type(16))) float f32x16;
typedef __attribute__((ext_vector_type(4))) unsigned int u32x4;

#define HIDDEN 1024
#define HEADS 16
#define HD 64
#define NB 4
#define T_ 2048
#define M_ROWS (NB * T_)  // 8192
#define SCL2 0.18033688f  // log2(e)/sqrt(64)

__device__ __forceinline__ unsigned short f2bf(float x) {
  unsigned u = __builtin_bit_cast(unsigned, x);
  u += 0x7fff + ((u >> 16) & 1);
  return (unsigned short)(u >> 16);
}

// pack two f32 -> two bf16 (round-half-up) in one u32 via v_perm
__device__ __forceinline__ unsigned pk2(float a, float b) {
  unsigned ua = __builtin_bit_cast(unsigned, a) + 0x8000u;
  unsigned ub = __builtin_bit_cast(unsigned, b) + 0x8000u;
  return __builtin_amdgcn_perm(ub, ua, 0x07060302);
}

__device__ __forceinline__ f32x4 mfma16(bf16x8 a, bf16x8 b, f32x4 c) {
  return __builtin_amdgcn_mfma_f32_16x16x32_bf16(a, b, c, 0, 0, 0);
}
__device__ __forceinline__ f32x16 mfma32(bf16x8 a, bf16x8 b, f32x16 c) {
  return __builtin_amdgcn_mfma_f32_32x32x16_bf16(a, b, c, 0, 0, 0);
}

__device__ __forceinline__ void lds16(const void* g, void* l) {
  __builtin_amdgcn_global_load_lds(
      (const __attribute__((address_space(1))) unsigned int*)g,
      (__attribute__((address_space(3))) unsigned int*)l, 16, 0, 0);
}

__device__ __forceinline__ bf16x8 ldg8(const unsigned short* p) {
  return __builtin_bit_cast(bf16x8, *(const u32x4*)p);
}

// ---------------- f32 -> bf16 convert ----------------
__global__ void cvt_bf16(const float* __restrict__ in,
                         unsigned short* __restrict__ out, int n4) {
  int i = blockIdx.x * blockDim.x + threadIdx.x;
  int stride = gridDim.x * blockDim.x;
  for (; i < n4; i += stride) {
    float4 v = ((const float4*)in)[i];
    ushort4 o;
    o.x = f2bf(v.x); o.y = f2bf(v.y); o.z = f2bf(v.z); o.w = f2bf(v.w);
    ((ushort4*)out)[i] = o;
  }
}

// ---------------- 128x128 MFMA GEMM, C = A * B^T (+bias), m97 structure ----
template <int EPI>
__global__ __launch_bounds__(256) void gemm_bt(
    const unsigned short* __restrict__ A, const unsigned short* __restrict__ Bm,
    const float* __restrict__ bias, unsigned short* __restrict__ Qb,
    unsigned short* __restrict__ Kb, unsigned short* __restrict__ Vtb,
    float* __restrict__ Cf, int M, int N, int K) {
  __shared__ __align__(16) unsigned short Al[128 * 32];
  __shared__ __align__(16) unsigned short Bl[128 * 32];
  const int tid = threadIdx.x;
  const int w = tid >> 6, lane = tid & 63;
  const int l16 = lane & 15, grp = lane >> 4;
  const int brow0 = blockIdx.y * 128;
  const int bcol0 = blockIdx.x * 128;
  const int wrow = (w >> 1) * 64, wcol = (w & 1) * 64;

  f32x4 acc[4][4];
#pragma unroll
  for (int i = 0; i < 4; i++)
#pragma unroll
    for (int j = 0; j < 4; j++) acc[i][j] = (f32x4){0.f, 0.f, 0.f, 0.f};

  for (int k0 = 0; k0 < K; k0 += 32) {
    __syncthreads();
#pragma unroll
    for (int i = 0; i < 2; i++) {
      int off = (w * 2 + i) * 1024 + lane * 16;  // byte offset in 8KB tile
      int row = off >> 6;
      int cole = (off & 63) >> 1;
      lds16(A + (size_t)(brow0 + row) * K + k0 + cole,
            (char*)Al + (w * 2 + i) * 1024);
      lds16(Bm + (size_t)(bcol0 + row) * K + k0 + cole,
            (char*)Bl + (w * 2 + i) * 1024);
    }
    __syncthreads();
    bf16x8 av[4], bv[4];
#pragma unroll
    for (int m = 0; m < 4; m++)
      av[m] = __builtin_bit_cast(
          bf16x8, *(const u32x4*)&Al[(wrow + m * 16 + l16) * 32 + grp * 8]);
#pragma unroll
    for (int n = 0; n < 4; n++)
      bv[n] = __builtin_bit_cast(
          bf16x8, *(const u32x4*)&Bl[(wcol + n * 16 + l16) * 32 + grp * 8]);
#pragma unroll
    for (int m = 0; m < 4; m++)
#pragma unroll
      for (int n = 0; n < 4; n++) acc[m][n] = mfma16(av[m], bv[n], acc[m][n]);
  }

#pragma unroll
  for (int m = 0; m < 4; m++) {
#pragma unroll
    for (int n = 0; n < 4; n++) {
      int col = bcol0 + wcol + n * 16 + l16;
      int row0 = brow0 + wrow + m * 16 + grp * 4;
      float bs = bias[col];
      if (EPI == 0) {
        int part = col >> 10, rem = col & 1023;
        int h = rem >> 6, d = rem & 63;
#pragma unroll
        for (int r = 0; r < 4; r++) {
          int rw = row0 + r;
          int b = rw >> 11, t = rw & 2047;
          unsigned short val = f2bf(acc[m][n][r] + bs);
          size_t bh = (size_t)(b * 16 + h);
          if (part == 0)
            Qb[(bh * T_ + t) * HD + d] = val;
          else if (part == 1)
            Kb[(bh * T_ + t) * HD + d] = val;
          else
            Vtb[(bh * HD + d) * T_ + t] = val;
        }
      } else {
#pragma unroll
        for (int r = 0; r < 4; r++)
          Cf[(size_t)(row0 + r) * N + col] = acc[m][n][r] + bs;
      }
    }
  }
}

// ---------------- causal flash attention, swapped 32x32x16 ----------------
// 2048 blocks x 128 thr (2 waves), ONE query tile per wave (4096 waves =
// 4 waves/SIMD at VGPR 108; r7 lesson: never force launch_bounds below the
// natural register need -> spills). bh = xcd + 8*(j&7): 8 heads/XCD K/V
// L2-fit. qt = 63-(2*(j>>3)+wv): heavy tiles dispatched first.
// All cross-lane: proven __shfl_xor(.,32); NO permlane self-swap (r2-r5).

#define PF(KF, VF, KC)                                          \
  do {                                                          \
    int kt_ = (KC) * 32;                                        \
    KF[0] = ldg8(&Kh[(size_t)(kt_ + l31) * HD + hi * 8]);       \
    KF[1] = ldg8(&Kh[(size_t)(kt_ + l31) * HD + 16 + hi * 8]);  \
    KF[2] = ldg8(&Kh[(size_t)(kt_ + l31) * HD + 32 + hi * 8]);  \
    KF[3] = ldg8(&Kh[(size_t)(kt_ + l31) * HD + 48 + hi * 8]);  \
    VF[0] = ldg8(&Vh[(size_t)l31 * T_ + kt_ + hi * 8]);         \
    VF[1] = ldg8(&Vh[(size_t)l31 * T_ + kt_ + 16 + hi * 8]);    \
    VF[2] = ldg8(&Vh[(size_t)(32 + l31) * T_ + kt_ + hi * 8]);  \
    VF[3] = ldg8(&Vh[(size_t)(32 + l31) * T_ + kt_ + 16 + hi * 8]); \
  } while (0)

#define CHUNK(KF, VF, MASKED)                                                \
  do {                                                                       \
    f32x16 sa;                                                               \
    _Pragma("unroll") for (int r = 0; r < 16; r++) sa[r] = 0.f;              \
    sa = mfma32(KF[0], qf[0], sa);                                           \
    sa = mfma32(KF[1], qf[1], sa);                                           \
    sa = mfma32(KF[2], qf[2], sa);                                           \
    sa = mfma32(KF[3], qf[3], sa);                                           \
    float sv[16];                                                            \
    _Pragma("unroll") for (int r = 0; r < 16; r++) {                         \
      sv[r] = sa[r] * SCL2;                                                  \
      if (MASKED) {                                                          \
        int key = (r & 3) + 8 * (r >> 2) + 4 * hi;                           \
        if (key > l31) sv[r] = -1e30f;                                       \
      }                                                                      \
    }                                                                        \
    float mx = sv[0];                                                        \
    _Pragma("unroll") for (int r = 1; r < 16; r++) mx = fmaxf(mx, sv[r]);    \
    mx = fmaxf(mx, __shfl_xor(mx, 32));                                      \
    if (mx > rm + 10.f) { /* defer-max */                                    \
      float c = exp2f(rm - mx);                                              \
      rl *= c;                                                               \
      _Pragma("unroll") for (int r = 0; r < 16; r++) {                       \
        o0[r] *= c;                                                          \
        o1[r] *= c;                                                          \
      }                                                                      \
      rm = mx;                                                               \
    }                                                                        \
    float rs = 0.f, pv[16];                                                  \
    _Pragma("unroll") for (int r = 0; r < 16; r++) {                         \
      pv[r] = exp2f(sv[r] - rm);                                             \
      rs += pv[r];                                                           \
    }                                                                        \
    rs += __shfl_xor(rs, 32);                                                \
    rl += rs;                                                                \
    unsigned wd[8], xd[8];                                                   \
    _Pragma("unroll") for (int j = 0; j < 8; j++)                            \
        wd[j] = pk2(pv[2 * j], pv[2 * j + 1]);                               \
    _Pragma("unroll") for (int j = 0; j < 8; j++)                            \
        xd[j] = (unsigned)__shfl_xor((int)wd[j], 32);                        \
    u32x4 pa0u, pa1u;                                                        \
    pa0u.x = hi ? xd[2] : wd[0];                                             \
    pa0u.y = hi ? xd[3] : wd[1];                                             \
    pa0u.z = hi ? wd[2] : xd[0];                                             \
    pa0u.w = hi ? wd[3] : xd[1];                                             \
    pa1u.x = hi ? xd[6] : wd[4];                                             \
    pa1u.y = hi ? xd[7] : wd[5];                                             \
    pa1u.z = hi ? wd[6] : xd[4];                                             \
    pa1u.w = hi ? wd[7] : xd[5];                                             \
    bf16x8 pa0 = __builtin_bit_cast(bf16x8, pa0u);                           \
    bf16x8 pa1 = __builtin_bit_cast(bf16x8, pa1u);                           \
    o0 = mfma32(VF[0], pa0, o0);                                             \
    o0 = mfma32(VF[1], pa1, o0);                                             \
    o1 = mfma32(VF[2], pa0, o1);                                             \
    o1 = mfma32(VF[3], pa1, o1);                                             \
  } while (0)

__global__ __launch_bounds__(128, 2) void attn32(
    const unsigned short* __restrict__ Q, const unsigned short* __restrict__ K,
    const unsigned short* __restrict__ Vt, unsigned short* __restrict__ Ao) {
  const int i = blockIdx.x;
  const int xcd = i & 7, j = i >> 3;           // j 0..255
  const int bh = xcd + 8 * (j & 7);            // 8 heads per XCD: K/V L2-fit
  const int wv = threadIdx.x >> 6, lane = threadIdx.x & 63;
  const int l31 = lane & 31, hi = lane >> 5;
  const int qt = 63 - (2 * (j >> 3) + wv);     // heavy query tiles first
  const unsigned short* Qh = Q + (size_t)bh * T_ * HD;
  const unsigned short* Kh = K + (size_t)bh * T_ * HD;
  const unsigned short* Vh = Vt + (size_t)bh * HD * T_;
  const int b_ = bh >> 4, h_ = bh & 15;

  bf16x8 qf[4], kA[4], vA[4], kB[4], vB[4];
  f32x16 o0, o1;
  float rm, rl;

  const int qbase = qt * 32;
#pragma unroll
  for (int st = 0; st < 4; st++)
    qf[st] = ldg8(&Qh[(size_t)(qbase + l31) * HD + st * 16 + hi * 8]);
#pragma unroll
  for (int r = 0; r < 16; r++) { o0[r] = 0.f; o1[r] = 0.f; }
  rm = -1e30f;
  rl = 0.f;

  PF(kA, vA, 0);
  int kc = 0;
  while (kc + 2 <= qt) {
    PF(kB, vB, kc + 1);
    CHUNK(kA, vA, 0);
    PF(kA, vA, kc + 2);
    CHUNK(kB, vB, 0);
    kc += 2;
  }
  if (kc < qt) {
    PF(kB, vB, kc + 1);
    CHUNK(kA, vA, 0);
    CHUNK(kB, vB, 1);
  } else {
    CHUNK(kA, vA, 1);
  }

  float inv = 1.f / rl;
  const size_t base = ((size_t)b_ * T_ + qbase + l31) * HIDDEN + h_ * HD + hi * 4;
#pragma unroll
  for (int g = 0; g < 4; g++) {
    uint2 u;
    u.x = pk2(o0[4 * g] * inv, o0[4 * g + 1] * inv);
    u.y = pk2(o0[4 * g + 2] * inv, o0[4 * g + 3] * inv);
    *(uint2*)&Ao[base + g * 8] = u;
  }
#pragma unroll
  for (int g = 0; g < 4; g++) {
    uint2 u;
    u.x = pk2(o1[4 * g] * inv, o1[4 * g + 1] * inv);
    u.y = pk2(o1[4 * g + 2] * inv, o1[4 * g + 3] * inv);
    *(uint2*)&Ao[base + 32 + g * 8] = u;
  }
}

extern "C" void kernel_launch(void* const* d_in, const int* in_sizes, int n_in,
                              void* d_out, int out_size, void* d_ws,
                              size_t ws_size, hipStream_t stream) {
  const float* data = (const float*)d_in[0];
  const float* qkvw = (const float*)d_in[1];
  const float* qkvb = (const float*)d_in[2];
  const float* outw = (const float*)d_in[3];
  const float* outb = (const float*)d_in[4];
  float* out = (float*)d_out;
  char* ws = (char*)d_ws;

  unsigned short* dataBf = (unsigned short*)(ws);             // 16 MiB, reused as attnO
  unsigned short* qkvwBf = (unsigned short*)(ws + 16777216);  // 6 MiB
  unsigned short* outwBf = (unsigned short*)(ws + 23068672);  // 2 MiB
  unsigned short* Qb = (unsigned short*)(ws + 25165824);      // 16 MiB
  unsigned short* Kb = (unsigned short*)(ws + 41943040);      // 16 MiB
  unsigned short* Vtb = (unsigned short*)(ws + 58720256);     // 16 MiB
  unsigned short* attnO = dataBf;  // safe: dataBf dead after QKV GEMM

  cvt_bf16<<<2048, 256, 0, stream>>>(data, dataBf, (M_ROWS * HIDDEN) / 4);
  cvt_bf16<<<1024, 256, 0, stream>>>(qkvw, qkvwBf, (3 * HIDDEN * HIDDEN) / 4);
  cvt_bf16<<<512, 256, 0, stream>>>(outw, outwBf, (HIDDEN * HIDDEN) / 4);

  gemm_bt<0><<<dim3(24, 64), 256, 0, stream>>>(dataBf, qkvwBf, qkvb, Qb, Kb,
                                               Vtb, nullptr, M_ROWS, 3 * HIDDEN,
                                               HIDDEN);
  attn32<<<2048, 128, 0, stream>>>(Qb, Kb, Vtb, attnO);
  gemm_bt<1><<<dim3(8, 64), 256, 0, stream>>>(attnO, outwBf, outb, nullptr,
                                              nullptr, nullptr, out, M_ROWS,
                                              HIDDEN, HIDDEN);
}

// Round 9
// 278.643 us; speedup vs baseline: 1.3447x; 1.0579x over previous
//
#include <hip/hip_runtime.h>
#include <hip/hip_bf16.h>
#include <stdint.h>

typedef __attribute__((ext_vector_type(8))) __bf16 bf16x8;
typedef __attribute__((ext_vector_type(4))) float f32x4;
typedef __attribute__((ext_vector_type(16))) float f32x16;
typedef __attribute__((ext_vector_type(4))) unsigned int u32x4;

#define HIDDEN 1024
#define HEADS 16
#define HD 64
#define NB 4
#define T_ 2048
#define M_ROWS (NB * T_)  // 8192
#define SCL2 0.18033688f  // log2(e)/sqrt(64)
#define FIXM 32.0f        // fixed softmax shift (exact-cancel in normalize)

__device__ __forceinline__ unsigned short f2bf(float x) {
  unsigned u = __builtin_bit_cast(unsigned, x);
  u += 0x7fff + ((u >> 16) & 1);
  return (unsigned short)(u >> 16);
}

// pack two f32 -> two bf16 (round-half-up) in one u32 via v_perm
__device__ __forceinline__ unsigned pk2(float a, float b) {
  unsigned ua = __builtin_bit_cast(unsigned, a) + 0x8000u;
  unsigned ub = __builtin_bit_cast(unsigned, b) + 0x8000u;
  return __builtin_amdgcn_perm(ub, ua, 0x07060302);
}

__device__ __forceinline__ f32x4 mfma16(bf16x8 a, bf16x8 b, f32x4 c) {
  return __builtin_amdgcn_mfma_f32_16x16x32_bf16(a, b, c, 0, 0, 0);
}
__device__ __forceinline__ f32x16 mfma32(bf16x8 a, bf16x8 b, f32x16 c) {
  return __builtin_amdgcn_mfma_f32_32x32x16_bf16(a, b, c, 0, 0, 0);
}

__device__ __forceinline__ void lds16(const void* g, void* l) {
  __builtin_amdgcn_global_load_lds(
      (const __attribute__((address_space(1))) unsigned int*)g,
      (__attribute__((address_space(3))) unsigned int*)l, 16, 0, 0);
}

__device__ __forceinline__ bf16x8 ldg8(const unsigned short* p) {
  return __builtin_bit_cast(bf16x8, *(const u32x4*)p);
}

// ---------------- f32 -> bf16 convert ----------------
__global__ void cvt_bf16(const float* __restrict__ in,
                         unsigned short* __restrict__ out, int n4) {
  int i = blockIdx.x * blockDim.x + threadIdx.x;
  int stride = gridDim.x * blockDim.x;
  for (; i < n4; i += stride) {
    float4 v = ((const float4*)in)[i];
    ushort4 o;
    o.x = f2bf(v.x); o.y = f2bf(v.y); o.z = f2bf(v.z); o.w = f2bf(v.w);
    ((ushort4*)out)[i] = o;
  }
}

// ---------------- 128x128 MFMA GEMM, C = A * B^T (+bias), m97 structure ----
template <int EPI>
__global__ __launch_bounds__(256) void gemm_bt(
    const unsigned short* __restrict__ A, const unsigned short* __restrict__ Bm,
    const float* __restrict__ bias, unsigned short* __restrict__ Qb,
    unsigned short* __restrict__ Kb, unsigned short* __restrict__ Vtb,
    float* __restrict__ Cf, int M, int N, int K) {
  __shared__ __align__(16) unsigned short Al[128 * 32];
  __shared__ __align__(16) unsigned short Bl[128 * 32];
  const int tid = threadIdx.x;
  const int w = tid >> 6, lane = tid & 63;
  const int l16 = lane & 15, grp = lane >> 4;
  const int brow0 = blockIdx.y * 128;
  const int bcol0 = blockIdx.x * 128;
  const int wrow = (w >> 1) * 64, wcol = (w & 1) * 64;

  f32x4 acc[4][4];
#pragma unroll
  for (int i = 0; i < 4; i++)
#pragma unroll
    for (int j = 0; j < 4; j++) acc[i][j] = (f32x4){0.f, 0.f, 0.f, 0.f};

  for (int k0 = 0; k0 < K; k0 += 32) {
    __syncthreads();
#pragma unroll
    for (int i = 0; i < 2; i++) {
      int off = (w * 2 + i) * 1024 + lane * 16;  // byte offset in 8KB tile
      int row = off >> 6;
      int cole = (off & 63) >> 1;
      lds16(A + (size_t)(brow0 + row) * K + k0 + cole,
            (char*)Al + (w * 2 + i) * 1024);
      lds16(Bm + (size_t)(bcol0 + row) * K + k0 + cole,
            (char*)Bl + (w * 2 + i) * 1024);
    }
    __syncthreads();
    bf16x8 av[4], bv[4];
#pragma unroll
    for (int m = 0; m < 4; m++)
      av[m] = __builtin_bit_cast(
          bf16x8, *(const u32x4*)&Al[(wrow + m * 16 + l16) * 32 + grp * 8]);
#pragma unroll
    for (int n = 0; n < 4; n++)
      bv[n] = __builtin_bit_cast(
          bf16x8, *(const u32x4*)&Bl[(wcol + n * 16 + l16) * 32 + grp * 8]);
#pragma unroll
    for (int m = 0; m < 4; m++)
#pragma unroll
      for (int n = 0; n < 4; n++) acc[m][n] = mfma16(av[m], bv[n], acc[m][n]);
  }

#pragma unroll
  for (int m = 0; m < 4; m++) {
#pragma unroll
    for (int n = 0; n < 4; n++) {
      int col = bcol0 + wcol + n * 16 + l16;
      int row0 = brow0 + wrow + m * 16 + grp * 4;
      float bs = bias[col];
      if (EPI == 0) {
        int part = col >> 10, rem = col & 1023;
        int h = rem >> 6, d = rem & 63;
#pragma unroll
        for (int r = 0; r < 4; r++) {
          int rw = row0 + r;
          int b = rw >> 11, t = rw & 2047;
          unsigned short val = f2bf(acc[m][n][r] + bs);
          size_t bh = (size_t)(b * 16 + h);
          if (part == 0)
            Qb[(bh * T_ + t) * HD + d] = val;
          else if (part == 1)
            Kb[(bh * T_ + t) * HD + d] = val;
          else
            Vtb[(bh * HD + d) * T_ + t] = val;
        }
      } else {
#pragma unroll
        for (int r = 0; r < 4; r++)
          Cf[(size_t)(row0 + r) * N + col] = acc[m][n][r] + bs;
      }
    }
  }
}

// ---------------- causal flash attention, swapped 32x32x16 ----------------
// 1024 blocks x 128 thr (2 waves), wave runs tiles (p, 63-p) = 65 chunks:
// perfect balance (r6-proven structure, 135us). FIXED-max softmax: softmax
// is shift-invariant, scores bounded (|s*log2e| <~ 5), so exp2(s-32) needs
// no running max, no rescale, no per-chunk cross-half sums. Cross-half
// l-sum deferred to ONE shfl at tile end. All cross-lane: proven
// __shfl_xor(.,32); NO permlane self-swap (r2-r5 miscompile).

#define PF(KF, VF, KC)                                          \
  do {                                                          \
    int kt_ = (KC) * 32;                                        \
    KF[0] = ldg8(&Kh[(size_t)(kt_ + l31) * HD + hi * 8]);       \
    KF[1] = ldg8(&Kh[(size_t)(kt_ + l31) * HD + 16 + hi * 8]);  \
    KF[2] = ldg8(&Kh[(size_t)(kt_ + l31) * HD + 32 + hi * 8]);  \
    KF[3] = ldg8(&Kh[(size_t)(kt_ + l31) * HD + 48 + hi * 8]);  \
    VF[0] = ldg8(&Vh[(size_t)l31 * T_ + kt_ + hi * 8]);         \
    VF[1] = ldg8(&Vh[(size_t)l31 * T_ + kt_ + 16 + hi * 8]);    \
    VF[2] = ldg8(&Vh[(size_t)(32 + l31) * T_ + kt_ + hi * 8]);  \
    VF[3] = ldg8(&Vh[(size_t)(32 + l31) * T_ + kt_ + 16 + hi * 8]); \
  } while (0)

#define CHUNK(KF, VF, MASKED)                                                \
  do {                                                                       \
    f32x16 sa;                                                               \
    _Pragma("unroll") for (int r = 0; r < 16; r++) sa[r] = 0.f;              \
    sa = mfma32(KF[0], qf[0], sa);                                           \
    sa = mfma32(KF[1], qf[1], sa);                                           \
    sa = mfma32(KF[2], qf[2], sa);                                           \
    sa = mfma32(KF[3], qf[3], sa);                                           \
    float pv[16];                                                            \
    _Pragma("unroll") for (int r = 0; r < 16; r++) {                         \
      float arg = __builtin_fmaf(sa[r], SCL2, -FIXM);                        \
      if (MASKED) {                                                          \
        int key = (r & 3) + 8 * (r >> 2) + 4 * hi;                           \
        if (key > l31) arg = -1e30f;                                         \
      }                                                                      \
      pv[r] = exp2f(arg);                                                    \
      rl += pv[r];                                                           \
    }                                                                        \
    unsigned wd[8], xd[8];                                                   \
    _Pragma("unroll") for (int j = 0; j < 8; j++)                            \
        wd[j] = pk2(pv[2 * j], pv[2 * j + 1]);                               \
    _Pragma("unroll") for (int j = 0; j < 8; j++)                            \
        xd[j] = (unsigned)__shfl_xor((int)wd[j], 32);                        \
    u32x4 pa0u, pa1u;                                                        \
    pa0u.x = hi ? xd[2] : wd[0];                                             \
    pa0u.y = hi ? xd[3] : wd[1];                                             \
    pa0u.z = hi ? wd[2] : xd[0];                                             \
    pa0u.w = hi ? wd[3] : xd[1];                                             \
    pa1u.x = hi ? xd[6] : wd[4];                                             \
    pa1u.y = hi ? xd[7] : wd[5];                                             \
    pa1u.z = hi ? wd[6] : xd[4];                                             \
    pa1u.w = hi ? wd[7] : xd[5];                                             \
    bf16x8 pa0 = __builtin_bit_cast(bf16x8, pa0u);                           \
    bf16x8 pa1 = __builtin_bit_cast(bf16x8, pa1u);                           \
    o0 = mfma32(VF[0], pa0, o0);                                             \
    o0 = mfma32(VF[1], pa1, o0);                                             \
    o1 = mfma32(VF[2], pa0, o1);                                             \
    o1 = mfma32(VF[3], pa1, o1);                                             \
  } while (0)

#define TILE(QT)                                                           \
  do {                                                                     \
    const int qt = (QT);                                                   \
    const int qbase = qt * 32;                                             \
    _Pragma("unroll") for (int st = 0; st < 4; st++) qf[st] =              \
        ldg8(&Qh[(size_t)(qbase + l31) * HD + st * 16 + hi * 8]);          \
    _Pragma("unroll") for (int r = 0; r < 16; r++) {                       \
      o0[r] = 0.f;                                                         \
      o1[r] = 0.f;                                                         \
    }                                                                      \
    rl = 0.f;                                                              \
    PF(kA, vA, 0);                                                         \
    int kc = 0;                                                            \
    while (kc + 2 <= qt) {                                                 \
      PF(kB, vB, kc + 1);                                                  \
      CHUNK(kA, vA, 0);                                                    \
      PF(kA, vA, kc + 2);                                                  \
      CHUNK(kB, vB, 0);                                                    \
      kc += 2;                                                             \
    }                                                                      \
    if (kc < qt) {                                                         \
      PF(kB, vB, kc + 1);                                                  \
      CHUNK(kA, vA, 0);                                                    \
      CHUNK(kB, vB, 1);                                                    \
    } else {                                                               \
      CHUNK(kA, vA, 1);                                                    \
    }                                                                      \
    float rlt = rl + __shfl_xor(rl, 32);                                   \
    float inv = 1.f / rlt;                                                 \
    const size_t base =                                                    \
        ((size_t)b_ * T_ + qbase + l31) * HIDDEN + h_ * HD + hi * 4;       \
    _Pragma("unroll") for (int g = 0; g < 4; g++) {                        \
      uint2 u;                                                             \
      u.x = pk2(o0[4 * g] * inv, o0[4 * g + 1] * inv);                     \
      u.y = pk2(o0[4 * g + 2] * inv, o0[4 * g + 3] * inv);                 \
      *(uint2*)&Ao[base + g * 8] = u;                                      \
    }                                                                      \
    _Pragma("unroll") for (int g = 0; g < 4; g++) {                        \
      uint2 u;                                                             \
      u.x = pk2(o1[4 * g] * inv, o1[4 * g + 1] * inv);                     \
      u.y = pk2(o1[4 * g + 2] * inv, o1[4 * g + 3] * inv);                 \
      *(uint2*)&Ao[base + 32 + g * 8] = u;                                 \
    }                                                                      \
  } while (0)

__global__ __launch_bounds__(128, 2) void attn32(
    const unsigned short* __restrict__ Q, const unsigned short* __restrict__ K,
    const unsigned short* __restrict__ Vt, unsigned short* __restrict__ Ao) {
  const int i = blockIdx.x;
  const int xcd = i & 7, sub = i >> 3;          // sub 0..127
  const int bh = xcd + 8 * (sub >> 4);          // 8 heads per XCD: K/V L2-fit
  const int wv = threadIdx.x >> 6, lane = threadIdx.x & 63;
  const int l31 = lane & 31, hi = lane >> 5;
  const int p = (sub & 15) * 2 + wv;            // 0..31: tiles (p, 63-p)
  const unsigned short* Qh = Q + (size_t)bh * T_ * HD;
  const unsigned short* Kh = K + (size_t)bh * T_ * HD;
  const unsigned short* Vh = Vt + (size_t)bh * HD * T_;
  const int b_ = bh >> 4, h_ = bh & 15;

  bf16x8 qf[4], kA[4], vA[4], kB[4], vB[4];
  f32x16 o0, o1;
  float rl;

  TILE(p);
  TILE(63 - p);
}

extern "C" void kernel_launch(void* const* d_in, const int* in_sizes, int n_in,
                              void* d_out, int out_size, void* d_ws,
                              size_t ws_size, hipStream_t stream) {
  const float* data = (const float*)d_in[0];
  const float* qkvw = (const float*)d_in[1];
  const float* qkvb = (const float*)d_in[2];
  const float* outw = (const float*)d_in[3];
  const float* outb = (const float*)d_in[4];
  float* out = (float*)d_out;
  char* ws = (char*)d_ws;

  unsigned short* dataBf = (unsigned short*)(ws);             // 16 MiB, reused as attnO
  unsigned short* qkvwBf = (unsigned short*)(ws + 16777216);  // 6 MiB
  unsigned short* outwBf = (unsigned short*)(ws + 23068672);  // 2 MiB
  unsigned short* Qb = (unsigned short*)(ws + 25165824);      // 16 MiB
  unsigned short* Kb = (unsigned short*)(ws + 41943040);      // 16 MiB
  unsigned short* Vtb = (unsigned short*)(ws + 58720256);     // 16 MiB
  unsigned short* attnO = dataBf;  // safe: dataBf dead after QKV GEMM

  cvt_bf16<<<2048, 256, 0, stream>>>(data, dataBf, (M_ROWS * HIDDEN) / 4);
  cvt_bf16<<<1024, 256, 0, stream>>>(qkvw, qkvwBf, (3 * HIDDEN * HIDDEN) / 4);
  cvt_bf16<<<512, 256, 0, stream>>>(outw, outwBf, (HIDDEN * HIDDEN) / 4);

  gemm_bt<0><<<dim3(24, 64), 256, 0, stream>>>(dataBf, qkvwBf, qkvb, Qb, Kb,
                                               Vtb, nullptr, M_ROWS, 3 * HIDDEN,
                                               HIDDEN);
  attn32<<<1024, 128, 0, stream>>>(Qb, Kb, Vtb, attnO);
  gemm_bt<1><<<dim3(8, 64), 256, 0, stream>>>(attnO, outwBf, outb, nullptr,
                                              nullptr, nullptr, out, M_ROWS,
                                              HIDDEN, HIDDEN);
}

// Round 10
// 259.351 us; speedup vs baseline: 1.4448x; 1.0744x over previous
//
#include <hip/hip_runtime.h>
#include <hip/hip_bf16.h>
#include <stdint.h>

typedef __attribute__((ext_vector_type(8))) __bf16 bf16x8;
typedef __attribute__((ext_vector_type(4))) float f32x4;
typedef __attribute__((ext_vector_type(16))) float f32x16;
typedef __attribute__((ext_vector_type(4))) unsigned int u32x4;

#define HIDDEN 1024
#define HEADS 16
#define HD 64
#define NB 4
#define T_ 2048
#define M_ROWS (NB * T_)  // 8192
#define SCL2 0.18033688f  // log2(e)/sqrt(64)
#define FIXM 32.0f        // fixed softmax shift (exact-cancel in normalize)

__device__ __forceinline__ unsigned short f2bf(float x) {
  unsigned u = __builtin_bit_cast(unsigned, x);
  u += 0x7fff + ((u >> 16) & 1);
  return (unsigned short)(u >> 16);
}

// pack two f32 -> two bf16 (round-half-up) in one u32 via v_perm
__device__ __forceinline__ unsigned pk2(float a, float b) {
  unsigned ua = __builtin_bit_cast(unsigned, a) + 0x8000u;
  unsigned ub = __builtin_bit_cast(unsigned, b) + 0x8000u;
  return __builtin_amdgcn_perm(ub, ua, 0x07060302);
}

__device__ __forceinline__ f32x4 mfma16(bf16x8 a, bf16x8 b, f32x4 c) {
  return __builtin_amdgcn_mfma_f32_16x16x32_bf16(a, b, c, 0, 0, 0);
}
__device__ __forceinline__ f32x16 mfma32(bf16x8 a, bf16x8 b, f32x16 c) {
  return __builtin_amdgcn_mfma_f32_32x32x16_bf16(a, b, c, 0, 0, 0);
}

__device__ __forceinline__ void lds16(const void* g, void* l) {
  __builtin_amdgcn_global_load_lds(
      (const __attribute__((address_space(1))) unsigned int*)g,
      (__attribute__((address_space(3))) unsigned int*)l, 16, 0, 0);
}

__device__ __forceinline__ bf16x8 ldg8(const unsigned short* p) {
  return __builtin_bit_cast(bf16x8, *(const u32x4*)p);
}

// ---------------- f32 -> bf16 convert ----------------
__global__ void cvt_bf16(const float* __restrict__ in,
                         unsigned short* __restrict__ out, int n4) {
  int i = blockIdx.x * blockDim.x + threadIdx.x;
  int stride = gridDim.x * blockDim.x;
  for (; i < n4; i += stride) {
    float4 v = ((const float4*)in)[i];
    ushort4 o;
    o.x = f2bf(v.x); o.y = f2bf(v.y); o.z = f2bf(v.z); o.w = f2bf(v.w);
    ((ushort4*)out)[i] = o;
  }
}

// ---------------- 128x128 MFMA GEMM, C = A * B^T (+bias), m97 structure ----
// EPI 0 scatters V^T with a KEY-SLOT PERMUTATION inside each 32-key group:
// slot s(k) = (r&7) + 8*((k>>2)&1) + 16*(r>>3), r=(k&3)+4*(k>>3). This makes
// the attention PV contraction ordering match S^T's natural lane layout ->
// the P cross-half shfl exchange disappears (see attn32).
template <int EPI>
__global__ __launch_bounds__(256) void gemm_bt(
    const unsigned short* __restrict__ A, const unsigned short* __restrict__ Bm,
    const float* __restrict__ bias, unsigned short* __restrict__ Qb,
    unsigned short* __restrict__ Kb, unsigned short* __restrict__ Vtb,
    float* __restrict__ Cf, int M, int N, int K) {
  __shared__ __align__(16) unsigned short Al[128 * 32];
  __shared__ __align__(16) unsigned short Bl[128 * 32];
  const int tid = threadIdx.x;
  const int w = tid >> 6, lane = tid & 63;
  const int l16 = lane & 15, grp = lane >> 4;
  const int brow0 = blockIdx.y * 128;
  const int bcol0 = blockIdx.x * 128;
  const int wrow = (w >> 1) * 64, wcol = (w & 1) * 64;

  f32x4 acc[4][4];
#pragma unroll
  for (int i = 0; i < 4; i++)
#pragma unroll
    for (int j = 0; j < 4; j++) acc[i][j] = (f32x4){0.f, 0.f, 0.f, 0.f};

  for (int k0 = 0; k0 < K; k0 += 32) {
    __syncthreads();
#pragma unroll
    for (int i = 0; i < 2; i++) {
      int off = (w * 2 + i) * 1024 + lane * 16;  // byte offset in 8KB tile
      int row = off >> 6;
      int cole = (off & 63) >> 1;
      lds16(A + (size_t)(brow0 + row) * K + k0 + cole,
            (char*)Al + (w * 2 + i) * 1024);
      lds16(Bm + (size_t)(bcol0 + row) * K + k0 + cole,
            (char*)Bl + (w * 2 + i) * 1024);
    }
    __syncthreads();
    bf16x8 av[4], bv[4];
#pragma unroll
    for (int m = 0; m < 4; m++)
      av[m] = __builtin_bit_cast(
          bf16x8, *(const u32x4*)&Al[(wrow + m * 16 + l16) * 32 + grp * 8]);
#pragma unroll
    for (int n = 0; n < 4; n++)
      bv[n] = __builtin_bit_cast(
          bf16x8, *(const u32x4*)&Bl[(wcol + n * 16 + l16) * 32 + grp * 8]);
#pragma unroll
    for (int m = 0; m < 4; m++)
#pragma unroll
      for (int n = 0; n < 4; n++) acc[m][n] = mfma16(av[m], bv[n], acc[m][n]);
  }

#pragma unroll
  for (int m = 0; m < 4; m++) {
#pragma unroll
    for (int n = 0; n < 4; n++) {
      int col = bcol0 + wcol + n * 16 + l16;
      int row0 = brow0 + wrow + m * 16 + grp * 4;
      float bs = bias[col];
      if (EPI == 0) {
        int part = col >> 10, rem = col & 1023;
        int h = rem >> 6, d = rem & 63;
#pragma unroll
        for (int r = 0; r < 4; r++) {
          int rw = row0 + r;
          int b = rw >> 11, t = rw & 2047;
          unsigned short val = f2bf(acc[m][n][r] + bs);
          size_t bh = (size_t)(b * 16 + h);
          if (part == 0)
            Qb[(bh * T_ + t) * HD + d] = val;
          else if (part == 1)
            Kb[(bh * T_ + t) * HD + d] = val;
          else {
            int k = t & 31;
            int rr = (k & 3) + 4 * (k >> 3);
            int s = (rr & 7) + 8 * ((k >> 2) & 1) + 16 * (rr >> 3);
            Vtb[(bh * HD + d) * T_ + (t & ~31) + s] = val;
          }
        }
      } else {
#pragma unroll
        for (int r = 0; r < 4; r++)
          Cf[(size_t)(row0 + r) * N + col] = acc[m][n][r] + bs;
      }
    }
  }
}

// ---------------- causal flash attention, swapped 32x32x16 ----------------
// 1024 blocks x 128 thr (2 waves), wave runs tiles (p, 63-p) = 65 chunks:
// perfect balance. FIXED-max softmax (shift-invariant, scores bounded).
// V^T stored KEY-PERMUTED (see gemm_bt) so PV's B-operand is the natural
// S^T lane layout: P packs straight from pv[] registers -> ZERO cross-lane
// ops in the chunk loop. Single shfl_xor(32) l-sum per tile (proven form;
// NO permlane self-swap - r2-r5 miscompile).

#define PF(KF, VF, KC)                                          \
  do {                                                          \
    int kt_ = (KC) * 32;                                        \
    KF[0] = ldg8(&Kh[(size_t)(kt_ + l31) * HD + hi * 8]);       \
    KF[1] = ldg8(&Kh[(size_t)(kt_ + l31) * HD + 16 + hi * 8]);  \
    KF[2] = ldg8(&Kh[(size_t)(kt_ + l31) * HD + 32 + hi * 8]);  \
    KF[3] = ldg8(&Kh[(size_t)(kt_ + l31) * HD + 48 + hi * 8]);  \
    VF[0] = ldg8(&Vh[(size_t)l31 * T_ + kt_ + hi * 8]);         \
    VF[1] = ldg8(&Vh[(size_t)l31 * T_ + kt_ + 16 + hi * 8]);    \
    VF[2] = ldg8(&Vh[(size_t)(32 + l31) * T_ + kt_ + hi * 8]);  \
    VF[3] = ldg8(&Vh[(size_t)(32 + l31) * T_ + kt_ + 16 + hi * 8]); \
  } while (0)

#define CHUNK(KF, VF, MASKED)                                                \
  do {                                                                       \
    f32x16 sa;                                                               \
    _Pragma("unroll") for (int r = 0; r < 16; r++) sa[r] = 0.f;              \
    sa = mfma32(KF[0], qf[0], sa);                                           \
    sa = mfma32(KF[1], qf[1], sa);                                           \
    sa = mfma32(KF[2], qf[2], sa);                                           \
    sa = mfma32(KF[3], qf[3], sa);                                           \
    float pv[16];                                                            \
    _Pragma("unroll") for (int r = 0; r < 16; r++) {                         \
      float arg = __builtin_fmaf(sa[r], SCL2, -FIXM);                        \
      if (MASKED) {                                                          \
        int key = (r & 3) + 8 * (r >> 2) + 4 * hi;                           \
        if (key > l31) arg = -1e30f;                                         \
      }                                                                      \
      pv[r] = exp2f(arg);                                                    \
      rl += pv[r];                                                           \
    }                                                                        \
    u32x4 pa0u, pa1u;                                                        \
    pa0u.x = pk2(pv[0], pv[1]);                                              \
    pa0u.y = pk2(pv[2], pv[3]);                                              \
    pa0u.z = pk2(pv[4], pv[5]);                                              \
    pa0u.w = pk2(pv[6], pv[7]);                                              \
    pa1u.x = pk2(pv[8], pv[9]);                                              \
    pa1u.y = pk2(pv[10], pv[11]);                                            \
    pa1u.z = pk2(pv[12], pv[13]);                                            \
    pa1u.w = pk2(pv[14], pv[15]);                                            \
    bf16x8 pa0 = __builtin_bit_cast(bf16x8, pa0u);                           \
    bf16x8 pa1 = __builtin_bit_cast(bf16x8, pa1u);                           \
    o0 = mfma32(VF[0], pa0, o0);                                             \
    o0 = mfma32(VF[1], pa1, o0);                                             \
    o1 = mfma32(VF[2], pa0, o1);                                             \
    o1 = mfma32(VF[3], pa1, o1);                                             \
  } while (0)

#define TILE(QT)                                                           \
  do {                                                                     \
    const int qt = (QT);                                                   \
    const int qbase = qt * 32;                                             \
    _Pragma("unroll") for (int st = 0; st < 4; st++) qf[st] =              \
        ldg8(&Qh[(size_t)(qbase + l31) * HD + st * 16 + hi * 8]);          \
    _Pragma("unroll") for (int r = 0; r < 16; r++) {                       \
      o0[r] = 0.f;                                                         \
      o1[r] = 0.f;                                                         \
    }                                                                      \
    rl = 0.f;                                                              \
    PF(kA, vA, 0);                                                         \
    int kc = 0;                                                            \
    while (kc + 2 <= qt) {                                                 \
      PF(kB, vB, kc + 1);                                                  \
      CHUNK(kA, vA, 0);                                                    \
      PF(kA, vA, kc + 2);                                                  \
      CHUNK(kB, vB, 0);                                                    \
      kc += 2;                                                             \
    }                                                                      \
    if (kc < qt) {                                                         \
      PF(kB, vB, kc + 1);                                                  \
      CHUNK(kA, vA, 0);                                                    \
      CHUNK(kB, vB, 1);                                                    \
    } else {                                                               \
      CHUNK(kA, vA, 1);                                                    \
    }                                                                      \
    float rlt = rl + __shfl_xor(rl, 32);                                   \
    float inv = 1.f / rlt;                                                 \
    const size_t base =                                                    \
        ((size_t)b_ * T_ + qbase + l31) * HIDDEN + h_ * HD + hi * 4;       \
    _Pragma("unroll") for (int g = 0; g < 4; g++) {                        \
      uint2 u;                                                             \
      u.x = pk2(o0[4 * g] * inv, o0[4 * g + 1] * inv);                     \
      u.y = pk2(o0[4 * g + 2] * inv, o0[4 * g + 3] * inv);                 \
      *(uint2*)&Ao[base + g * 8] = u;                                      \
    }                                                                      \
    _Pragma("unroll") for (int g = 0; g < 4; g++) {                        \
      uint2 u;                                                             \
      u.x = pk2(o1[4 * g] * inv, o1[4 * g + 1] * inv);                     \
      u.y = pk2(o1[4 * g + 2] * inv, o1[4 * g + 3] * inv);                 \
      *(uint2*)&Ao[base + 32 + g * 8] = u;                                 \
    }                                                                      \
  } while (0)

__global__ __launch_bounds__(128, 2) void attn32(
    const unsigned short* __restrict__ Q, const unsigned short* __restrict__ K,
    const unsigned short* __restrict__ Vt, unsigned short* __restrict__ Ao) {
  const int i = blockIdx.x;
  const int xcd = i & 7, sub = i >> 3;          // sub 0..127
  const int bh = xcd + 8 * (sub >> 4);          // 8 heads per XCD: K/V L2-fit
  const int wv = threadIdx.x >> 6, lane = threadIdx.x & 63;
  const int l31 = lane & 31, hi = lane >> 5;
  const int p = (sub & 15) * 2 + wv;            // 0..31: tiles (p, 63-p)
  const unsigned short* Qh = Q + (size_t)bh * T_ * HD;
  const unsigned short* Kh = K + (size_t)bh * T_ * HD;
  const unsigned short* Vh = Vt + (size_t)bh * HD * T_;
  const int b_ = bh >> 4, h_ = bh & 15;

  bf16x8 qf[4], kA[4], vA[4], kB[4], vB[4];
  f32x16 o0, o1;
  float rl;

  TILE(p);
  TILE(63 - p);
}

extern "C" void kernel_launch(void* const* d_in, const int* in_sizes, int n_in,
                              void* d_out, int out_size, void* d_ws,
                              size_t ws_size, hipStream_t stream) {
  const float* data = (const float*)d_in[0];
  const float* qkvw = (const float*)d_in[1];
  const float* qkvb = (const float*)d_in[2];
  const float* outw = (const float*)d_in[3];
  const float* outb = (const float*)d_in[4];
  float* out = (float*)d_out;
  char* ws = (char*)d_ws;

  unsigned short* dataBf = (unsigned short*)(ws);             // 16 MiB, reused as attnO
  unsigned short* qkvwBf = (unsigned short*)(ws + 16777216);  // 6 MiB
  unsigned short* outwBf = (unsigned short*)(ws + 23068672);  // 2 MiB
  unsigned short* Qb = (unsigned short*)(ws + 25165824);      // 16 MiB
  unsigned short* Kb = (unsigned short*)(ws + 41943040);      // 16 MiB
  unsigned short* Vtb = (unsigned short*)(ws + 58720256);     // 16 MiB
  unsigned short* attnO = dataBf;  // safe: dataBf dead after QKV GEMM

  cvt_bf16<<<2048, 256, 0, stream>>>(data, dataBf, (M_ROWS * HIDDEN) / 4);
  cvt_bf16<<<1024, 256, 0, stream>>>(qkvw, qkvwBf, (3 * HIDDEN * HIDDEN) / 4);
  cvt_bf16<<<512, 256, 0, stream>>>(outw, outwBf, (HIDDEN * HIDDEN) / 4);

  gemm_bt<0><<<dim3(24, 64), 256, 0, stream>>>(dataBf, qkvwBf, qkvb, Qb, Kb,
                                               Vtb, nullptr, M_ROWS, 3 * HIDDEN,
                                               HIDDEN);
  attn32<<<1024, 128, 0, stream>>>(Qb, Kb, Vtb, attnO);
  gemm_bt<1><<<dim3(8, 64), 256, 0, stream>>>(attnO, outwBf, outb, nullptr,
                                              nullptr, nullptr, out, M_ROWS,
                                              HIDDEN, HIDDEN);
}

// Round 11
// 202.683 us; speedup vs baseline: 1.8487x; 1.2796x over previous
//
#include <hip/hip_runtime.h>
#include <hip/hip_bf16.h>
#include <stdint.h>

typedef __attribute__((ext_vector_type(8))) __bf16 bf16x8;
typedef __attribute__((ext_vector_type(4))) float f32x4;
typedef __attribute__((ext_vector_type(16))) float f32x16;
typedef __attribute__((ext_vector_type(4))) unsigned int u32x4;

#define HIDDEN 1024
#define HEADS 16
#define HD 64
#define NB 4
#define T_ 2048
#define M_ROWS (NB * T_)  // 8192
#define SCL2 0.18033688f  // log2(e)/sqrt(64)
#define FIXM 32.0f        // fixed softmax shift (exact-cancel in normalize)

__device__ __forceinline__ unsigned short f2bf(float x) {
  unsigned u = __builtin_bit_cast(unsigned, x);
  u += 0x7fff + ((u >> 16) & 1);
  return (unsigned short)(u >> 16);
}

// pack two f32 -> two bf16 (round-half-up) in one u32 via v_perm
__device__ __forceinline__ unsigned pk2(float a, float b) {
  unsigned ua = __builtin_bit_cast(unsigned, a) + 0x8000u;
  unsigned ub = __builtin_bit_cast(unsigned, b) + 0x8000u;
  return __builtin_amdgcn_perm(ub, ua, 0x07060302);
}

__device__ __forceinline__ f32x4 mfma16(bf16x8 a, bf16x8 b, f32x4 c) {
  return __builtin_amdgcn_mfma_f32_16x16x32_bf16(a, b, c, 0, 0, 0);
}
__device__ __forceinline__ f32x16 mfma32(bf16x8 a, bf16x8 b, f32x16 c) {
  return __builtin_amdgcn_mfma_f32_32x32x16_bf16(a, b, c, 0, 0, 0);
}

__device__ __forceinline__ void lds16(const void* g, void* l) {
  __builtin_amdgcn_global_load_lds(
      (const __attribute__((address_space(1))) unsigned int*)g,
      (__attribute__((address_space(3))) unsigned int*)l, 16, 0, 0);
}

__device__ __forceinline__ bf16x8 ldg8(const unsigned short* p) {
  return __builtin_bit_cast(bf16x8, *(const u32x4*)p);
}

// ---------------- f32 -> bf16 convert ----------------
__global__ void cvt_bf16(const float* __restrict__ in,
                         unsigned short* __restrict__ out, int n4) {
  int i = blockIdx.x * blockDim.x + threadIdx.x;
  int stride = gridDim.x * blockDim.x;
  for (; i < n4; i += stride) {
    float4 v = ((const float4*)in)[i];
    ushort4 o;
    o.x = f2bf(v.x); o.y = f2bf(v.y); o.z = f2bf(v.z); o.w = f2bf(v.w);
    ((ushort4*)out)[i] = o;
  }
}

// ---------------- 128x128 MFMA GEMM, C = A * B^T (+bias), m97 structure ----
// EPI 0 scatters V^T with a KEY-SLOT PERMUTATION inside each 32-key group:
// slot s(k) = (r&7) + 8*((k>>2)&1) + 16*(r>>3), r=(k&3)+4*(k>>3). This makes
// the attention PV contraction ordering match S^T's natural lane layout.
template <int EPI>
__global__ __launch_bounds__(256) void gemm_bt(
    const unsigned short* __restrict__ A, const unsigned short* __restrict__ Bm,
    const float* __restrict__ bias, unsigned short* __restrict__ Qb,
    unsigned short* __restrict__ Kb, unsigned short* __restrict__ Vtb,
    float* __restrict__ Cf, int M, int N, int K) {
  __shared__ __align__(16) unsigned short Al[128 * 32];
  __shared__ __align__(16) unsigned short Bl[128 * 32];
  const int tid = threadIdx.x;
  const int w = tid >> 6, lane = tid & 63;
  const int l16 = lane & 15, grp = lane >> 4;
  const int brow0 = blockIdx.y * 128;
  const int bcol0 = blockIdx.x * 128;
  const int wrow = (w >> 1) * 64, wcol = (w & 1) * 64;

  f32x4 acc[4][4];
#pragma unroll
  for (int i = 0; i < 4; i++)
#pragma unroll
    for (int j = 0; j < 4; j++) acc[i][j] = (f32x4){0.f, 0.f, 0.f, 0.f};

  for (int k0 = 0; k0 < K; k0 += 32) {
    __syncthreads();
#pragma unroll
    for (int i = 0; i < 2; i++) {
      int off = (w * 2 + i) * 1024 + lane * 16;  // byte offset in 8KB tile
      int row = off >> 6;
      int cole = (off & 63) >> 1;
      lds16(A + (size_t)(brow0 + row) * K + k0 + cole,
            (char*)Al + (w * 2 + i) * 1024);
      lds16(Bm + (size_t)(bcol0 + row) * K + k0 + cole,
            (char*)Bl + (w * 2 + i) * 1024);
    }
    __syncthreads();
    bf16x8 av[4], bv[4];
#pragma unroll
    for (int m = 0; m < 4; m++)
      av[m] = __builtin_bit_cast(
          bf16x8, *(const u32x4*)&Al[(wrow + m * 16 + l16) * 32 + grp * 8]);
#pragma unroll
    for (int n = 0; n < 4; n++)
      bv[n] = __builtin_bit_cast(
          bf16x8, *(const u32x4*)&Bl[(wcol + n * 16 + l16) * 32 + grp * 8]);
#pragma unroll
    for (int m = 0; m < 4; m++)
#pragma unroll
      for (int n = 0; n < 4; n++) acc[m][n] = mfma16(av[m], bv[n], acc[m][n]);
  }

#pragma unroll
  for (int m = 0; m < 4; m++) {
#pragma unroll
    for (int n = 0; n < 4; n++) {
      int col = bcol0 + wcol + n * 16 + l16;
      int row0 = brow0 + wrow + m * 16 + grp * 4;
      float bs = bias[col];
      if (EPI == 0) {
        int part = col >> 10, rem = col & 1023;
        int h = rem >> 6, d = rem & 63;
#pragma unroll
        for (int r = 0; r < 4; r++) {
          int rw = row0 + r;
          int b = rw >> 11, t = rw & 2047;
          unsigned short val = f2bf(acc[m][n][r] + bs);
          size_t bh = (size_t)(b * 16 + h);
          if (part == 0)
            Qb[(bh * T_ + t) * HD + d] = val;
          else if (part == 1)
            Kb[(bh * T_ + t) * HD + d] = val;
          else {
            int k = t & 31;
            int rr = (k & 3) + 4 * (k >> 3);
            int s = (rr & 7) + 8 * ((k >> 2) & 1) + 16 * (rr >> 3);
            Vtb[(bh * HD + d) * T_ + (t & ~31) + s] = val;
          }
        }
      } else {
#pragma unroll
        for (int r = 0; r < 4; r++)
          Cf[(size_t)(row0 + r) * N + col] = acc[m][n][r] + bs;
      }
    }
  }
}

// ---------------- causal flash attention, LDS-shared K/V ----------------
// 1024 blocks x 256 thr (4 waves). Block = head bh x q-tiles g*4..g*4+3.
// Per 32-key chunk: block stages K(4KB)+V(4KB) into double-buffered LDS via
// global_load_lds (linear dest, PRE-SWIZZLED source: unit^=(row&7)); all
// waves ds_read_b128 with the same swizzle (rule: both-sides-or-neither).
// V stored d-pair-packed: row j = [d=j | d=32+j], so V reads use the same
// swizzle pattern as K. 2-phase pipeline: STAGE(next); compute(cur);
// __syncthreads (drains vmcnt). Chunk math identical to r10 (fixed-max
// softmax, permuted-V PV, zero cross-lane in loop).
// Mapping: bh=i&63 (8 heads/XCD); g: i<512 -> 15-(i>>6), else (i-512)>>6
// -> co-resident block pairs sum to constant work per CU.

__global__ __launch_bounds__(256, 3) void attn32(
    const unsigned short* __restrict__ Q, const unsigned short* __restrict__ K,
    const unsigned short* __restrict__ Vt, unsigned short* __restrict__ Ao) {
  __shared__ __align__(16) unsigned short Kl[2][32 * 64];  // 4KB per buf
  __shared__ __align__(16) unsigned short Vl[2][32 * 64];  // 4KB per buf
  const int i = blockIdx.x;
  const int bh = i & 63;
  const int g = (i < 512) ? (15 - (i >> 6)) : ((i - 512) >> 6);
  const int wv = threadIdx.x >> 6, lane = threadIdx.x & 63;
  const int l31 = lane & 31, hi = lane >> 5;
  const int qt = g * 4 + wv;       // this wave's q-tile
  const int maxqt = g * 4 + 3;     // block chunk bound
  const unsigned short* Qh = Q + (size_t)bh * T_ * HD;
  const unsigned short* Kh = K + (size_t)bh * T_ * HD;
  const unsigned short* Vh = Vt + (size_t)bh * HD * T_;
  const int b_ = bh >> 4, h_ = bh & 15;

  // staging: thread tid covers LDS row sj=tid>>3, 16B-unit su=tid&7 (linear
  // dest); source pre-swizzled: true unit sup = su ^ (sj&7).
  const int sj = threadIdx.x >> 3, su = threadIdx.x & 7;
  const int sup = su ^ (sj & 7);
  const unsigned short* ksrc = Kh + sj * HD + sup * 8;  // +kt*HD per chunk
  const unsigned short* vsrc =
      Vh + (size_t)(sj + 32 * (sup >> 2)) * T_ + (sup & 3) * 8;  // +kt
  char* kdst0 = (char*)&Kl[0][0] + wv * 1024;
  char* kdst1 = (char*)&Kl[1][0] + wv * 1024;
  char* vdst0 = (char*)&Vl[0][0] + wv * 1024;
  char* vdst1 = (char*)&Vl[1][0] + wv * 1024;

#define STAGE(B, KC)                                         \
  do {                                                       \
    int kt_ = (KC) * 32;                                     \
    lds16(ksrc + (size_t)kt_ * HD, (B) ? kdst1 : kdst0);     \
    lds16(vsrc + kt_, (B) ? vdst1 : vdst0);                  \
  } while (0)

  // per-wave read offsets (swizzled): frag ks -> row l31, unit 2*ks+hi
  int rdoff[4];
#pragma unroll
  for (int ks = 0; ks < 4; ks++)
    rdoff[ks] = l31 * 128 + (((2 * ks + hi) ^ (l31 & 7)) << 4);

  bf16x8 qf[4];
  const int qbase = qt * 32;
#pragma unroll
  for (int st = 0; st < 4; st++)
    qf[st] = ldg8(&Qh[(size_t)(qbase + l31) * HD + st * 16 + hi * 8]);

  f32x16 o0, o1;
#pragma unroll
  for (int r = 0; r < 16; r++) { o0[r] = 0.f; o1[r] = 0.f; }
  float rl = 0.f;

#define CHUNK(B, MASKED)                                                     \
  do {                                                                       \
    const char* kb = (const char*)&Kl[(B)][0];                               \
    const char* vb = (const char*)&Vl[(B)][0];                               \
    bf16x8 KF[4], VF[4];                                                     \
    _Pragma("unroll") for (int ks = 0; ks < 4; ks++) {                       \
      KF[ks] = __builtin_bit_cast(bf16x8, *(const u32x4*)(kb + rdoff[ks]));  \
      VF[ks] = __builtin_bit_cast(bf16x8, *(const u32x4*)(vb + rdoff[ks]));  \
    }                                                                        \
    f32x16 sa;                                                               \
    _Pragma("unroll") for (int r = 0; r < 16; r++) sa[r] = 0.f;              \
    sa = mfma32(KF[0], qf[0], sa);                                           \
    sa = mfma32(KF[1], qf[1], sa);                                           \
    sa = mfma32(KF[2], qf[2], sa);                                           \
    sa = mfma32(KF[3], qf[3], sa);                                           \
    float pv[16];                                                            \
    _Pragma("unroll") for (int r = 0; r < 16; r++) {                         \
      float arg = __builtin_fmaf(sa[r], SCL2, -FIXM);                        \
      if (MASKED) {                                                          \
        int key = (r & 3) + 8 * (r >> 2) + 4 * hi;                           \
        if (key > l31) arg = -1e30f;                                         \
      }                                                                      \
      pv[r] = exp2f(arg);                                                    \
      rl += pv[r];                                                           \
    }                                                                        \
    u32x4 pa0u, pa1u;                                                        \
    pa0u.x = pk2(pv[0], pv[1]);                                              \
    pa0u.y = pk2(pv[2], pv[3]);                                              \
    pa0u.z = pk2(pv[4], pv[5]);                                              \
    pa0u.w = pk2(pv[6], pv[7]);                                              \
    pa1u.x = pk2(pv[8], pv[9]);                                              \
    pa1u.y = pk2(pv[10], pv[11]);                                            \
    pa1u.z = pk2(pv[12], pv[13]);                                            \
    pa1u.w = pk2(pv[14], pv[15]);                                            \
    bf16x8 pa0 = __builtin_bit_cast(bf16x8, pa0u);                           \
    bf16x8 pa1 = __builtin_bit_cast(bf16x8, pa1u);                           \
    o0 = mfma32(VF[0], pa0, o0);                                             \
    o0 = mfma32(VF[1], pa1, o0);                                             \
    o1 = mfma32(VF[2], pa0, o1);                                             \
    o1 = mfma32(VF[3], pa1, o1);                                             \
  } while (0)

  STAGE(0, 0);
  __syncthreads();  // drains vmcnt: buf0 ready
  int cur = 0;
  for (int kc = 0; kc <= maxqt; kc++) {
    if (kc < maxqt) STAGE(cur ^ 1, kc + 1);  // async prefetch next chunk
    if (kc < qt) {
      CHUNK(cur, 0);
    } else if (kc == qt) {
      CHUNK(cur, 1);
    }
    __syncthreads();  // stage complete + all reads of cur done
    cur ^= 1;
  }

  float rlt = rl + __shfl_xor(rl, 32);
  float inv = 1.f / rlt;
  const size_t base =
      ((size_t)b_ * T_ + qbase + l31) * HIDDEN + h_ * HD + hi * 4;
#pragma unroll
  for (int gg = 0; gg < 4; gg++) {
    uint2 u;
    u.x = pk2(o0[4 * gg] * inv, o0[4 * gg + 1] * inv);
    u.y = pk2(o0[4 * gg + 2] * inv, o0[4 * gg + 3] * inv);
    *(uint2*)&Ao[base + gg * 8] = u;
  }
#pragma unroll
  for (int gg = 0; gg < 4; gg++) {
    uint2 u;
    u.x = pk2(o1[4 * gg] * inv, o1[4 * gg + 1] * inv);
    u.y = pk2(o1[4 * gg + 2] * inv, o1[4 * gg + 3] * inv);
    *(uint2*)&Ao[base + 32 + gg * 8] = u;
  }
#undef STAGE
#undef CHUNK
}

extern "C" void kernel_launch(void* const* d_in, const int* in_sizes, int n_in,
                              void* d_out, int out_size, void* d_ws,
                              size_t ws_size, hipStream_t stream) {
  const float* data = (const float*)d_in[0];
  const float* qkvw = (const float*)d_in[1];
  const float* qkvb = (const float*)d_in[2];
  const float* outw = (const float*)d_in[3];
  const float* outb = (const float*)d_in[4];
  float* out = (float*)d_out;
  char* ws = (char*)d_ws;

  unsigned short* dataBf = (unsigned short*)(ws);             // 16 MiB, reused as attnO
  unsigned short* qkvwBf = (unsigned short*)(ws + 16777216);  // 6 MiB
  unsigned short* outwBf = (unsigned short*)(ws + 23068672);  // 2 MiB
  unsigned short* Qb = (unsigned short*)(ws + 25165824);      // 16 MiB
  unsigned short* Kb = (unsigned short*)(ws + 41943040);      // 16 MiB
  unsigned short* Vtb = (unsigned short*)(ws + 58720256);     // 16 MiB
  unsigned short* attnO = dataBf;  // safe: dataBf dead after QKV GEMM

  cvt_bf16<<<2048, 256, 0, stream>>>(data, dataBf, (M_ROWS * HIDDEN) / 4);
  cvt_bf16<<<1024, 256, 0, stream>>>(qkvw, qkvwBf, (3 * HIDDEN * HIDDEN) / 4);
  cvt_bf16<<<512, 256, 0, stream>>>(outw, outwBf, (HIDDEN * HIDDEN) / 4);

  gemm_bt<0><<<dim3(24, 64), 256, 0, stream>>>(dataBf, qkvwBf, qkvb, Qb, Kb,
                                               Vtb, nullptr, M_ROWS, 3 * HIDDEN,
                                               HIDDEN);
  attn32<<<1024, 256, 0, stream>>>(Qb, Kb, Vtb, attnO);
  gemm_bt<1><<<dim3(8, 64), 256, 0, stream>>>(attnO, outwBf, outb, nullptr,
                                              nullptr, nullptr, out, M_ROWS,
                                              HIDDEN, HIDDEN);
}

// Round 12
// 188.091 us; speedup vs baseline: 1.9921x; 1.0776x over previous
//
#include <hip/hip_runtime.h>
#include <hip/hip_bf16.h>
#include <stdint.h>

typedef __attribute__((ext_vector_type(8))) __bf16 bf16x8;
typedef __attribute__((ext_vector_type(4))) float f32x4;
typedef __attribute__((ext_vector_type(16))) float f32x16;
typedef __attribute__((ext_vector_type(4))) unsigned int u32x4;

#define HIDDEN 1024
#define HEADS 16
#define HD 64
#define NB 4
#define T_ 2048
#define M_ROWS (NB * T_)  // 8192
#define SCL2 0.18033688f  // log2(e)/sqrt(64)
#define FIXM 32.0f        // fixed softmax shift (exact-cancel in normalize)

__device__ __forceinline__ unsigned short f2bf(float x) {
  unsigned u = __builtin_bit_cast(unsigned, x);
  u += 0x7fff + ((u >> 16) & 1);
  return (unsigned short)(u >> 16);
}

__device__ __forceinline__ unsigned pk2(float a, float b) {
  unsigned ua = __builtin_bit_cast(unsigned, a) + 0x8000u;
  unsigned ub = __builtin_bit_cast(unsigned, b) + 0x8000u;
  return __builtin_amdgcn_perm(ub, ua, 0x07060302);
}

__device__ __forceinline__ f32x4 mfma16(bf16x8 a, bf16x8 b, f32x4 c) {
  return __builtin_amdgcn_mfma_f32_16x16x32_bf16(a, b, c, 0, 0, 0);
}
__device__ __forceinline__ f32x16 mfma32(bf16x8 a, bf16x8 b, f32x16 c) {
  return __builtin_amdgcn_mfma_f32_32x32x16_bf16(a, b, c, 0, 0, 0);
}

__device__ __forceinline__ void lds16(const void* g, void* l) {
  __builtin_amdgcn_global_load_lds(
      (const __attribute__((address_space(1))) unsigned int*)g,
      (__attribute__((address_space(3))) unsigned int*)l, 16, 0, 0);
}

__device__ __forceinline__ bf16x8 ldg8(const unsigned short* p) {
  return __builtin_bit_cast(bf16x8, *(const u32x4*)p);
}

// ---------------- f32 -> bf16 convert ----------------
__global__ void cvt_bf16(const float* __restrict__ in,
                         unsigned short* __restrict__ out, int n4) {
  int i = blockIdx.x * blockDim.x + threadIdx.x;
  int stride = gridDim.x * blockDim.x;
  for (; i < n4; i += stride) {
    float4 v = ((const float4*)in)[i];
    ushort4 o;
    o.x = f2bf(v.x); o.y = f2bf(v.y); o.z = f2bf(v.z); o.w = f2bf(v.w);
    ((ushort4*)out)[i] = o;
  }
}

// ============ 8-phase counted-vmcnt GEMM, C = A * B^T (+bias) =============
// BM=256 BN=128 BK=64, 512 thr (8 waves 4Mx2N, 64x64/wave, acc 4x4).
// Triple-buffered LDS (3 x 48KB = 144KB): tile t computes from buf c while
// t+1 is landed and t+2's 6 global_load_lds are IN FLIGHT -> steady-state
// s_waitcnt vmcnt(6), never 0 (T3+T4). Per K-tile 4 phases: {ds_read frags,
// 2 stage-issues, s_barrier, setprio1, 8 MFMA, setprio0, s_barrier} (T5).
// T2 both-sides XOR swizzle: LDS linear [row][unit], staged from pre-swizzled
// global source unit^=(row&7); ds_read applies same XOR (r11-attn-proven).
// Raw s_barrier only (no __syncthreads - it drains vmcnt).
// K=1024 fixed (16 tiles). EPI 0: QKV scatter epilogue (+V key-permute);
// EPI 1: f32 C+bias. Grid: 32 x NT, XCD-chunked bijective swizzle.

#define MF4(AM, B0, B1, B2, B3, M)              \
  acc[M][0] = mfma16(AM, B0, acc[M][0]);        \
  acc[M][1] = mfma16(AM, B1, acc[M][1]);        \
  acc[M][2] = mfma16(AM, B2, acc[M][2]);        \
  acc[M][3] = mfma16(AM, B3, acc[M][3]);

#define RD(BUF, OFF) \
  __builtin_bit_cast(bf16x8, *(const u32x4*)((BUF) + (OFF)))

template <int EPI, int NT>
__global__ __launch_bounds__(512, 2) void gemm8(
    const unsigned short* __restrict__ A, const unsigned short* __restrict__ Bm,
    const float* __restrict__ bias, unsigned short* __restrict__ Qb,
    unsigned short* __restrict__ Kb, unsigned short* __restrict__ Vtb,
    float* __restrict__ Cf) {
  constexpr int K = 1024;
  constexpr int N = NT * 128;
  __shared__ __align__(16) char LB[147456];  // 3 x (A 32KB + B 16KB)
  const int tid = threadIdx.x;
  const int wv = tid >> 6, lane = tid & 63;
  const int l16 = lane & 15, grp = lane >> 4;
  const int wm = wv >> 1, wn = wv & 1;
  const int bid = blockIdx.x;
  const int sw = (bid & 7) * (NT * 4) + (bid >> 3);  // XCD-chunked, bijective
  const int by = sw / NT, bx = sw % NT;
  const int brow0 = by * 256, bcol0 = bx * 128;

  // staging: thread covers (row = i*64 + srow, unit = lane&7) linear LDS;
  // source column pre-swizzled by row&7 (both-sides rule).
  const int srow = wv * 8 + (lane >> 3);
  const int sunit = (lane & 7) ^ (srow & 7);
  const unsigned short* pA = A + (size_t)(brow0 + srow) * K + sunit * 8;
  const unsigned short* pB = Bm + (size_t)(bcol0 + srow) * K + sunit * 8;

  // ds_read swizzled unit offsets (row&7 == l16&7 for all frag rows)
  const int rsw = l16 & 7;
  const int swu0 = ((grp) ^ rsw) << 4;        // kk=0: units 0..3
  const int swu1 = ((4 + grp) ^ rsw) << 4;    // kk=1: units 4..7
  const int aBase = (wm * 64 + l16) * 128;
  const int bBase = (wn * 64 + l16) * 128;

#define BUFA(c) (LB + (c) * 49152)
#define BUFB(c) (LB + (c) * 49152 + 32768)
#define STAGE_A01(c, t)                                          \
  do {                                                           \
    lds16(pA + (size_t)(t) * 64, BUFA(c) + wv * 1024);           \
    lds16(pA + (size_t)64 * K + (t) * 64,                        \
          BUFA(c) + 8192 + wv * 1024);                           \
  } while (0)
#define STAGE_A23(c, t)                                          \
  do {                                                           \
    lds16(pA + (size_t)128 * K + (t) * 64,                       \
          BUFA(c) + 16384 + wv * 1024);                          \
    lds16(pA + (size_t)192 * K + (t) * 64,                       \
          BUFA(c) + 24576 + wv * 1024);                          \
  } while (0)
#define STAGE_B01(c, t)                                          \
  do {                                                           \
    lds16(pB + (size_t)(t) * 64, BUFB(c) + wv * 1024);           \
    lds16(pB + (size_t)64 * K + (t) * 64,                        \
          BUFB(c) + 8192 + wv * 1024);                           \
  } while (0)

  f32x4 acc[4][4];
#pragma unroll
  for (int m = 0; m < 4; m++)
#pragma unroll
    for (int n = 0; n < 4; n++) acc[m][n] = (f32x4){0.f, 0.f, 0.f, 0.f};

#define GTILE(BA, BB, S1, S2, S3, ENDW)                                \
  {                                                                    \
    bf16x8 b00 = RD(BB, bBase + swu0), b01 = RD(BB, bBase + 2048 + swu0), \
           b02 = RD(BB, bBase + 4096 + swu0),                          \
           b03 = RD(BB, bBase + 6144 + swu0);                          \
    bf16x8 a0 = RD(BA, aBase + swu0), a1 = RD(BA, aBase + 2048 + swu0); \
    S1;                                                                \
    __builtin_amdgcn_s_barrier();                                      \
    __builtin_amdgcn_s_setprio(1);                                     \
    MF4(a0, b00, b01, b02, b03, 0)                                     \
    MF4(a1, b00, b01, b02, b03, 1)                                     \
    __builtin_amdgcn_s_setprio(0);                                     \
    __builtin_amdgcn_s_barrier();                                      \
    bf16x8 b10 = RD(BB, bBase + swu1), b11 = RD(BB, bBase + 2048 + swu1), \
           b12 = RD(BB, bBase + 4096 + swu1),                          \
           b13 = RD(BB, bBase + 6144 + swu1);                          \
    a0 = RD(BA, aBase + swu1);                                         \
    a1 = RD(BA, aBase + 2048 + swu1);                                  \
    S2;                                                                \
    __builtin_amdgcn_s_barrier();                                      \
    __builtin_amdgcn_s_setprio(1);                                     \
    MF4(a0, b10, b11, b12, b13, 0)                                     \
    MF4(a1, b10, b11, b12, b13, 1)                                     \
    __builtin_amdgcn_s_setprio(0);                                     \
    __builtin_amdgcn_s_barrier();                                      \
    a0 = RD(BA, aBase + 4096 + swu0);                                  \
    a1 = RD(BA, aBase + 6144 + swu0);                                  \
    S3;                                                                \
    __builtin_amdgcn_s_barrier();                                      \
    __builtin_amdgcn_s_setprio(1);                                     \
    MF4(a0, b00, b01, b02, b03, 2)                                     \
    MF4(a1, b00, b01, b02, b03, 3)                                     \
    __builtin_amdgcn_s_setprio(0);                                     \
    __builtin_amdgcn_s_barrier();                                      \
    a0 = RD(BA, aBase + 4096 + swu1);                                  \
    a1 = RD(BA, aBase + 6144 + swu1);                                  \
    __builtin_amdgcn_s_barrier();                                      \
    __builtin_amdgcn_s_setprio(1);                                     \
    MF4(a0, b10, b11, b12, b13, 2)                                     \
    MF4(a1, b10, b11, b12, b13, 3)                                     \
    __builtin_amdgcn_s_setprio(0);                                     \
    ENDW;                                                              \
    __builtin_amdgcn_s_barrier();                                      \
  }

  // prologue: stage tiles 0,1 -> bufs 0,1; wait tile0 (leave tile1 in flight)
  STAGE_A01(0, 0); STAGE_A23(0, 0); STAGE_B01(0, 0);
  STAGE_A01(1, 1); STAGE_A23(1, 1); STAGE_B01(1, 1);
  asm volatile("s_waitcnt vmcnt(6)" ::: "memory");
  __builtin_amdgcn_sched_barrier(0);
  __builtin_amdgcn_s_barrier();

  int c = 0, c2 = 2;
#pragma unroll 1
  for (int t = 0; t < 14; ++t) {
    const char* ba = BUFA(c);
    const char* bb = BUFB(c);
    GTILE(ba, bb, STAGE_A01(c2, t + 2), STAGE_A23(c2, t + 2),
          STAGE_B01(c2, t + 2),
          { asm volatile("s_waitcnt vmcnt(6)" ::: "memory");
            __builtin_amdgcn_sched_barrier(0); });
    c = (c == 2) ? 0 : c + 1;
    c2 = (c2 == 2) ? 0 : c2 + 1;
  }
  {  // t = 14: no stage; drain tile 15's loads
    const char* ba = BUFA(c);
    const char* bb = BUFB(c);
    GTILE(ba, bb, , , ,
          { asm volatile("s_waitcnt vmcnt(0)" ::: "memory");
            __builtin_amdgcn_sched_barrier(0); });
    c = (c == 2) ? 0 : c + 1;
  }
  {  // t = 15: last tile, no stage, no wait
    const char* ba = BUFA(c);
    const char* bb = BUFB(c);
    GTILE(ba, bb, , , , );
  }

  // epilogue (proven scatter, wave geometry 4Mx2N)
#pragma unroll
  for (int m = 0; m < 4; m++) {
#pragma unroll
    for (int n = 0; n < 4; n++) {
      int col = bcol0 + wn * 64 + n * 16 + l16;
      int row0 = brow0 + wm * 64 + m * 16 + grp * 4;
      float bs = bias[col];
      if (EPI == 0) {
        int part = col >> 10, rem = col & 1023;
        int h = rem >> 6, d = rem & 63;
#pragma unroll
        for (int r = 0; r < 4; r++) {
          int rw = row0 + r;
          int b = rw >> 11, t = rw & 2047;
          unsigned short val = f2bf(acc[m][n][r] + bs);
          size_t bh = (size_t)(b * 16 + h);
          if (part == 0)
            Qb[(bh * T_ + t) * HD + d] = val;
          else if (part == 1)
            Kb[(bh * T_ + t) * HD + d] = val;
          else {
            int k = t & 31;
            int rr = (k & 3) + 4 * (k >> 3);
            int s = (rr & 7) + 8 * ((k >> 2) & 1) + 16 * (rr >> 3);
            Vtb[(bh * HD + d) * T_ + (t & ~31) + s] = val;
          }
        }
      } else {
#pragma unroll
        for (int r = 0; r < 4; r++)
          Cf[(size_t)(row0 + r) * N + col] = acc[m][n][r] + bs;
      }
    }
  }
#undef BUFA
#undef BUFB
#undef STAGE_A01
#undef STAGE_A23
#undef STAGE_B01
#undef GTILE
}

// ---------------- causal flash attention, LDS-shared K/V (r11, proven) ----
__global__ __launch_bounds__(256, 3) void attn32(
    const unsigned short* __restrict__ Q, const unsigned short* __restrict__ K,
    const unsigned short* __restrict__ Vt, unsigned short* __restrict__ Ao) {
  __shared__ __align__(16) unsigned short Kl[2][32 * 64];
  __shared__ __align__(16) unsigned short Vl[2][32 * 64];
  const int i = blockIdx.x;
  const int bh = i & 63;
  const int g = (i < 512) ? (15 - (i >> 6)) : ((i - 512) >> 6);
  const int wv = threadIdx.x >> 6, lane = threadIdx.x & 63;
  const int l31 = lane & 31, hi = lane >> 5;
  const int qt = g * 4 + wv;
  const int maxqt = g * 4 + 3;
  const unsigned short* Qh = Q + (size_t)bh * T_ * HD;
  const unsigned short* Kh = K + (size_t)bh * T_ * HD;
  const unsigned short* Vh = Vt + (size_t)bh * HD * T_;
  const int b_ = bh >> 4, h_ = bh & 15;

  const int sj = threadIdx.x >> 3, su = threadIdx.x & 7;
  const int sup = su ^ (sj & 7);
  const unsigned short* ksrc = Kh + sj * HD + sup * 8;
  const unsigned short* vsrc =
      Vh + (size_t)(sj + 32 * (sup >> 2)) * T_ + (sup & 3) * 8;
  char* kdst0 = (char*)&Kl[0][0] + wv * 1024;
  char* kdst1 = (char*)&Kl[1][0] + wv * 1024;
  char* vdst0 = (char*)&Vl[0][0] + wv * 1024;
  char* vdst1 = (char*)&Vl[1][0] + wv * 1024;

#define STAGE(B, KC)                                     \
  do {                                                   \
    int kt_ = (KC) * 32;                                 \
    lds16(ksrc + (size_t)kt_ * HD, (B) ? kdst1 : kdst0); \
    lds16(vsrc + kt_, (B) ? vdst1 : vdst0);              \
  } while (0)

  int rdoff[4];
#pragma unroll
  for (int ks = 0; ks < 4; ks++)
    rdoff[ks] = l31 * 128 + (((2 * ks + hi) ^ (l31 & 7)) << 4);

  bf16x8 qf[4];
  const int qbase = qt * 32;
#pragma unroll
  for (int st = 0; st < 4; st++)
    qf[st] = ldg8(&Qh[(size_t)(qbase + l31) * HD + st * 16 + hi * 8]);

  f32x16 o0, o1;
#pragma unroll
  for (int r = 0; r < 16; r++) { o0[r] = 0.f; o1[r] = 0.f; }
  float rl = 0.f;

#define CHUNK(B, MASKED)                                                     \
  do {                                                                       \
    const char* kb = (const char*)&Kl[(B)][0];                               \
    const char* vb = (const char*)&Vl[(B)][0];                               \
    bf16x8 KF[4], VF[4];                                                     \
    _Pragma("unroll") for (int ks = 0; ks < 4; ks++) {                       \
      KF[ks] = __builtin_bit_cast(bf16x8, *(const u32x4*)(kb + rdoff[ks]));  \
      VF[ks] = __builtin_bit_cast(bf16x8, *(const u32x4*)(vb + rdoff[ks]));  \
    }                                                                        \
    f32x16 sa;                                                               \
    _Pragma("unroll") for (int r = 0; r < 16; r++) sa[r] = 0.f;              \
    sa = mfma32(KF[0], qf[0], sa);                                           \
    sa = mfma32(KF[1], qf[1], sa);                                           \
    sa = mfma32(KF[2], qf[2], sa);                                           \
    sa = mfma32(KF[3], qf[3], sa);                                           \
    float pv[16];                                                            \
    _Pragma("unroll") for (int r = 0; r < 16; r++) {                         \
      float arg = __builtin_fmaf(sa[r], SCL2, -FIXM);                        \
      if (MASKED) {                                                          \
        int key = (r & 3) + 8 * (r >> 2) + 4 * hi;                           \
        if (key > l31) arg = -1e30f;                                         \
      }                                                                      \
      pv[r] = exp2f(arg);                                                    \
      rl += pv[r];                                                           \
    }                                                                        \
    u32x4 pa0u, pa1u;                                                        \
    pa0u.x = pk2(pv[0], pv[1]);                                              \
    pa0u.y = pk2(pv[2], pv[3]);                                              \
    pa0u.z = pk2(pv[4], pv[5]);                                              \
    pa0u.w = pk2(pv[6], pv[7]);                                              \
    pa1u.x = pk2(pv[8], pv[9]);                                              \
    pa1u.y = pk2(pv[10], pv[11]);                                            \
    pa1u.z = pk2(pv[12], pv[13]);                                            \
    pa1u.w = pk2(pv[14], pv[15]);                                            \
    bf16x8 pa0 = __builtin_bit_cast(bf16x8, pa0u);                           \
    bf16x8 pa1 = __builtin_bit_cast(bf16x8, pa1u);                           \
    o0 = mfma32(VF[0], pa0, o0);                                             \
    o0 = mfma32(VF[1], pa1, o0);                                             \
    o1 = mfma32(VF[2], pa0, o1);                                             \
    o1 = mfma32(VF[3], pa1, o1);                                             \
  } while (0)

  STAGE(0, 0);
  __syncthreads();
  int cur = 0;
  for (int kc = 0; kc <= maxqt; kc++) {
    if (kc < maxqt) STAGE(cur ^ 1, kc + 1);
    if (kc < qt) {
      CHUNK(cur, 0);
    } else if (kc == qt) {
      CHUNK(cur, 1);
    }
    __syncthreads();
    cur ^= 1;
  }

  float rlt = rl + __shfl_xor(rl, 32);
  float inv = 1.f / rlt;
  const size_t base =
      ((size_t)b_ * T_ + qbase + l31) * HIDDEN + h_ * HD + hi * 4;
#pragma unroll
  for (int gg = 0; gg < 4; gg++) {
    uint2 u;
    u.x = pk2(o0[4 * gg] * inv, o0[4 * gg + 1] * inv);
    u.y = pk2(o0[4 * gg + 2] * inv, o0[4 * gg + 3] * inv);
    *(uint2*)&Ao[base + gg * 8] = u;
  }
#pragma unroll
  for (int gg = 0; gg < 4; gg++) {
    uint2 u;
    u.x = pk2(o1[4 * gg] * inv, o1[4 * gg + 1] * inv);
    u.y = pk2(o1[4 * gg + 2] * inv, o1[4 * gg + 3] * inv);
    *(uint2*)&Ao[base + 32 + gg * 8] = u;
  }
#undef STAGE
#undef CHUNK
}

extern "C" void kernel_launch(void* const* d_in, const int* in_sizes, int n_in,
                              void* d_out, int out_size, void* d_ws,
                              size_t ws_size, hipStream_t stream) {
  const float* data = (const float*)d_in[0];
  const float* qkvw = (const float*)d_in[1];
  const float* qkvb = (const float*)d_in[2];
  const float* outw = (const float*)d_in[3];
  const float* outb = (const float*)d_in[4];
  float* out = (float*)d_out;
  char* ws = (char*)d_ws;

  unsigned short* dataBf = (unsigned short*)(ws);             // 16 MiB, reused as attnO
  unsigned short* qkvwBf = (unsigned short*)(ws + 16777216);  // 6 MiB
  unsigned short* outwBf = (unsigned short*)(ws + 23068672);  // 2 MiB
  unsigned short* Qb = (unsigned short*)(ws + 25165824);      // 16 MiB
  unsigned short* Kb = (unsigned short*)(ws + 41943040);      // 16 MiB
  unsigned short* Vtb = (unsigned short*)(ws + 58720256);     // 16 MiB
  unsigned short* attnO = dataBf;  // safe: dataBf dead after QKV GEMM

  cvt_bf16<<<2048, 256, 0, stream>>>(data, dataBf, (M_ROWS * HIDDEN) / 4);
  cvt_bf16<<<1024, 256, 0, stream>>>(qkvw, qkvwBf, (3 * HIDDEN * HIDDEN) / 4);
  cvt_bf16<<<512, 256, 0, stream>>>(outw, outwBf, (HIDDEN * HIDDEN) / 4);

  gemm8<0, 24><<<768, 512, 0, stream>>>(dataBf, qkvwBf, qkvb, Qb, Kb, Vtb,
                                        nullptr);
  attn32<<<1024, 256, 0, stream>>>(Qb, Kb, Vtb, attnO);
  gemm8<1, 8><<<256, 512, 0, stream>>>(attnO, outwBf, outb, nullptr, nullptr,
                                       nullptr, out);
}